// Round 2
// baseline (1090.988 us; speedup 1.0000x reference)
//
#include <hip/hip_runtime.h>
#include <math.h>

#define B_ 8
#define N_ 2048
#define K_ 8
#define IN_ 5
#define BN_ (B_*N_)
#define NEDGE_ (BN_*K_)
#define GRP 8

// ---------------- kNN: brute-force top-8 smallest distances per point ----------------
__global__ __launch_bounds__(256) void knn_kernel(const float* __restrict__ points,
                                                  int* __restrict__ src) {
    int q = blockIdx.x * 256 + threadIdx.x;   // global point id; each block stays in one batch (2048%256==0)
    int b = q / N_;
    int n = q % N_;
    const float* pb = points + (size_t)b * N_ * IN_;
    float qx = pb[(size_t)n*IN_+0], qy = pb[(size_t)n*IN_+1], qz = pb[(size_t)n*IN_+2];
    float qsq = qx*qx + qy*qy + qz*qz;

    float bd[K_]; int bi[K_];
#pragma unroll
    for (int k = 0; k < K_; ++k) { bd[k] = INFINITY; bi[k] = 0x7FFFFFFF; }

    __shared__ float sp[256][4];
    for (int t0 = 0; t0 < N_; t0 += 256) {
        int j = t0 + threadIdx.x;
        float x = pb[(size_t)j*IN_+0], y = pb[(size_t)j*IN_+1], z = pb[(size_t)j*IN_+2];
        __syncthreads();
        sp[threadIdx.x][0] = x; sp[threadIdx.x][1] = y;
        sp[threadIdx.x][2] = z; sp[threadIdx.x][3] = x*x + y*y + z*z;
        __syncthreads();
        for (int jj = 0; jj < 256; ++jj) {
            float d = qsq + sp[jj][3] - 2.0f*(qx*sp[jj][0] + qy*sp[jj][1] + qz*sp[jj][2]);
            int jg = t0 + jj;
            if (jg == n) d += 1e10f;
            // lexicographic (d, idx) insert -> matches jax top_k tie-breaking
            if (d < bd[K_-1] || (d == bd[K_-1] && jg < bi[K_-1])) {
                float cd = d; int ci = jg;
#pragma unroll
                for (int p = 0; p < K_; ++p) {
                    bool lt = (cd < bd[p]) || (cd == bd[p] && ci < bi[p]);
                    float nd = lt ? cd : bd[p]; int ni = lt ? ci : bi[p];
                    float od = lt ? bd[p] : cd; int oi = lt ? bi[p] : ci;
                    bd[p] = nd; bi[p] = ni; cd = od; ci = oi;
                }
            }
        }
    }
#pragma unroll
    for (int k = 0; k < K_; ++k) src[(size_t)q*K_ + k] = b*N_ + bi[k];
}

// ---------------- weight prep: fold previous-layer BN affine into W ----------------
// A' = s .* (W_top - W_bot), B' = s .* W_bot
__global__ void prep_AB(const float* __restrict__ W, const float* __restrict__ scale,
                        float* __restrict__ Ap, float* __restrict__ Bp, int Cin, int Cout) {
    int idx = blockIdx.x * 256 + threadIdx.x;
    if (idx >= Cin*Cout) return;
    int d = idx / Cout;
    float s = scale ? scale[d] : 1.0f;
    float wt = W[idx];
    float wb = W[(size_t)Cin*Cout + idx];
    Ap[idx] = s * (wt - wb);
    Bp[idx] = s * wb;
}

// c' = b + shift @ W_top
__global__ void prep_c(const float* __restrict__ W, const float* __restrict__ shift,
                       const float* __restrict__ bias, float* __restrict__ cvec,
                       int Cin, int Cout) {
    int c = blockIdx.x * 64 + threadIdx.x;
    if (c >= Cout) return;
    float acc = bias[c];
    if (shift)
        for (int d = 0; d < Cin; ++d) acc += shift[d] * W[(size_t)d*Cout + c];
    cvec[c] = acc;
}

// ---------------- fp32 tiled GEMM: C[MxN] = A[MxK] @ B[KxN], M%64==0, N%64==0 ----------------
__global__ __launch_bounds__(256) void sgemm64(const float* __restrict__ A, const float* __restrict__ B,
                                               float* __restrict__ C, int M, int N, int K) {
    __shared__ float As[16][68];
    __shared__ float Bs[16][68];
    int bm = blockIdx.y * 64, bn = blockIdx.x * 64;
    int tid = threadIdx.x;
    int tm = (tid / 16) * 4;
    int tn = (tid % 16) * 4;
    float acc[4][4] = {};
    for (int k0 = 0; k0 < K; k0 += 16) {
        for (int e = tid; e < 64*16; e += 256) {
            int row = e >> 4, kk = e & 15;
            As[kk][row] = (k0+kk < K) ? A[(size_t)(bm+row)*K + k0+kk] : 0.0f;
        }
        for (int e = tid; e < 16*64; e += 256) {
            int kk = e >> 6, col = e & 63;
            Bs[kk][col] = (k0+kk < K) ? B[(size_t)(k0+kk)*N + bn+col] : 0.0f;
        }
        __syncthreads();
#pragma unroll
        for (int kk = 0; kk < 16; ++kk) {
            float4 a4 = *reinterpret_cast<const float4*>(&As[kk][tm]);
            float4 b4 = *reinterpret_cast<const float4*>(&Bs[kk][tn]);
            float av[4] = {a4.x, a4.y, a4.z, a4.w};
            float bv[4] = {b4.x, b4.y, b4.z, b4.w};
#pragma unroll
            for (int i = 0; i < 4; ++i)
#pragma unroll
                for (int j = 0; j < 4; ++j) acc[i][j] += av[i]*bv[j];
        }
        __syncthreads();
    }
#pragma unroll
    for (int i = 0; i < 4; ++i)
#pragma unroll
        for (int j = 0; j < 4; ++j)
            C[(size_t)(bm+tm+i)*N + bn+tn+j] = acc[i][j];
}

// ---------------- edge combine: h = P[dst] + Q[src] + c ; lrelu; per-dst max; BN partials ----------------
__global__ void combine_kernel(const float* __restrict__ P, const float* __restrict__ Q,
                               const float* __restrict__ cvec, const int* __restrict__ src,
                               float* __restrict__ m_out, float* __restrict__ partial, int C) {
    int c = threadIdx.x;                 // blockDim.x == C
    int i0 = blockIdx.x * GRP;
    float cv = cvec[c];
    float sum = 0.f, ssq = 0.f;
    for (int g = 0; g < GRP; ++g) {
        int i = i0 + g;
        float p = P[(size_t)i*C + c] + cv;
        float mx = -INFINITY;
#pragma unroll
        for (int k = 0; k < K_; ++k) {
            int s = src[(size_t)i*K_ + k];
            float h = p + Q[(size_t)s*C + c];
            float l = (h >= 0.f) ? h : 0.2f*h;
            sum += l; ssq += l*l;
            mx = fmaxf(mx, l);
        }
        m_out[(size_t)i*C + c] = mx;     // pre-affine max of lrelu
    }
    partial[(size_t)blockIdx.x*2*C + c]     = sum;
    partial[(size_t)blockIdx.x*2*C + C + c] = ssq;
}

// ---------------- BN stats reduce -> scale/shift (deterministic tree) ----------------
__global__ __launch_bounds__(256) void reduce_kernel(const float* __restrict__ partial, int nblocks, int C,
                              const float* __restrict__ g, const float* __restrict__ be,
                              float* __restrict__ scale, float* __restrict__ shift) {
    int c = blockIdx.x;
    float s0 = 0.f, s1 = 0.f;
    for (int blk = threadIdx.x; blk < nblocks; blk += 256) {
        s0 += partial[(size_t)blk*2*C + c];
        s1 += partial[(size_t)blk*2*C + C + c];
    }
    __shared__ float l0[256], l1[256];
    l0[threadIdx.x] = s0; l1[threadIdx.x] = s1;
    __syncthreads();
    for (int off = 128; off > 0; off >>= 1) {
        if (threadIdx.x < off) {
            l0[threadIdx.x] += l0[threadIdx.x + off];
            l1[threadIdx.x] += l1[threadIdx.x + off];
        }
        __syncthreads();
    }
    if (threadIdx.x == 0) {
        float mean = l0[0] / (float)NEDGE_;
        float var  = l1[0] / (float)NEDGE_ - mean*mean;
        float sc = g[c] * rsqrtf(var + 1e-5f);
        scale[c] = sc;
        shift[c] = be[c] - mean*sc;
    }
}

// ---------------- per-batch global max over N points (+apply BN affine) ----------------
__global__ __launch_bounds__(256) void batchmax_kernel(const float* __restrict__ m, const float* __restrict__ scale,
                                const float* __restrict__ shift, float* __restrict__ gfeat,
                                int C, int coff) {
    int b = blockIdx.x;
    int cl = threadIdx.x & 63;
    int c = blockIdx.y * 64 + cl;
    int stripe = threadIdx.x >> 6;  // 0..3
    const float* mb = m + (size_t)b*N_*C + c;
    float mx = -INFINITY;
    for (int n = stripe; n < N_; n += 4)
        mx = fmaxf(mx, mb[(size_t)n*C]);
    __shared__ float red[256];
    red[threadIdx.x] = mx;
    __syncthreads();
    if (stripe == 0) {
        float v = fmaxf(fmaxf(red[cl], red[cl+64]), fmaxf(red[cl+128], red[cl+192]));
        gfeat[b*448 + coff + c] = scale[c]*v + shift[c];   // FIX: was coff+cl, dropped blockIdx.y*64
    }
}

// ---------------- final head: gfeat@Wf1 + lrelu + BN(8 rows) + @Wf2 ----------------
__global__ __launch_bounds__(512) void final_kernel(const float* __restrict__ gfeat,
                             const float* __restrict__ Wf1, const float* __restrict__ bf1,
                             const float* __restrict__ gf, const float* __restrict__ bef,
                             const float* __restrict__ Wf2, const float* __restrict__ bf2,
                             float* __restrict__ out) {
    __shared__ float gf_s[B_][448];
    __shared__ float h_s[B_][512];
    int t = threadIdx.x;
    for (int e = t; e < B_*448; e += 512) gf_s[e/448][e%448] = gfeat[e];
    __syncthreads();
    float acc[B_];
#pragma unroll
    for (int r = 0; r < B_; ++r) acc[r] = bf1[t];
    for (int d = 0; d < 448; ++d) {
        float w = Wf1[(size_t)d*512 + t];
#pragma unroll
        for (int r = 0; r < B_; ++r) acc[r] += gf_s[r][d] * w;
    }
#pragma unroll
    for (int r = 0; r < B_; ++r) { float v = acc[r]; acc[r] = (v >= 0.f) ? v : 0.2f*v; }
    float mean = 0.f;
#pragma unroll
    for (int r = 0; r < B_; ++r) mean += acc[r];
    mean *= (1.0f/B_);
    float var = 0.f;
#pragma unroll
    for (int r = 0; r < B_; ++r) { float dd = acc[r] - mean; var += dd*dd; }
    var *= (1.0f/B_);
    float sc = gf[t] * rsqrtf(var + 1e-5f);
    float sh = bef[t] - mean*sc;
#pragma unroll
    for (int r = 0; r < B_; ++r) h_s[r][t] = acc[r]*sc + sh;
    __syncthreads();
    for (int e = t; e < B_*128; e += 512) {
        int r = e >> 7, c = e & 127;
        float a = bf2[c];
        for (int d = 0; d < 512; ++d) a += h_s[r][d] * Wf2[(size_t)d*128 + c];
        out[e] = a;
    }
}

// ---------------- host side ----------------
static void run_layer(const float* X, int Cin, int Cout,
                      const float* W, const float* b, const float* g, const float* be,
                      const float* scale_in, const float* shift_in,
                      float* Pb, float* Qb, float* Ap, float* Bp, float* cvec,
                      const int* src, float* m_out, float* partial,
                      float* scale_out, float* shift_out, hipStream_t stream) {
    int nAB = Cin * Cout;
    prep_AB<<<(nAB + 255)/256, 256, 0, stream>>>(W, scale_in, Ap, Bp, Cin, Cout);
    prep_c<<<(Cout + 63)/64, 64, 0, stream>>>(W, shift_in, b, cvec, Cin, Cout);
    sgemm64<<<dim3(Cout/64, BN_/64), 256, 0, stream>>>(X, Ap, Pb, BN_, Cout, Cin);
    sgemm64<<<dim3(Cout/64, BN_/64), 256, 0, stream>>>(X, Bp, Qb, BN_, Cout, Cin);
    combine_kernel<<<BN_/GRP, Cout, 0, stream>>>(Pb, Qb, cvec, src, m_out, partial, Cout);
    reduce_kernel<<<Cout, 256, 0, stream>>>(partial, BN_/GRP, Cout, g, be, scale_out, shift_out);
}

extern "C" void kernel_launch(void* const* d_in, const int* in_sizes, int n_in,
                              void* d_out, int out_size, void* d_ws, size_t ws_size,
                              hipStream_t stream) {
    (void)in_sizes; (void)n_in; (void)out_size; (void)ws_size;
    const float* points = (const float*)d_in[0];
    const float* W1 = (const float*)d_in[1];  const float* b1 = (const float*)d_in[2];
    const float* g1 = (const float*)d_in[3];  const float* be1 = (const float*)d_in[4];
    const float* W2 = (const float*)d_in[5];  const float* b2 = (const float*)d_in[6];
    const float* g2 = (const float*)d_in[7];  const float* be2 = (const float*)d_in[8];
    const float* W3 = (const float*)d_in[9];  const float* b3 = (const float*)d_in[10];
    const float* g3 = (const float*)d_in[11]; const float* be3 = (const float*)d_in[12];
    const float* Wf1 = (const float*)d_in[13]; const float* bf1 = (const float*)d_in[14];
    const float* gf = (const float*)d_in[15];  const float* bef = (const float*)d_in[16];
    const float* Wf2 = (const float*)d_in[17]; const float* bf2 = (const float*)d_in[18];
    float* out = (float*)d_out;

    size_t off = 0;
    char* base = (char*)d_ws;
    auto carve = [&](size_t bytes) -> void* {
        void* p = base + off;
        off += (bytes + 255) & ~(size_t)255;
        return p;
    };
    int*   src     = (int*)  carve((size_t)NEDGE_ * 4);
    float* Pb      = (float*)carve((size_t)BN_ * 256 * 4);
    float* Qb      = (float*)carve((size_t)BN_ * 256 * 4);
    float* m1      = (float*)carve((size_t)BN_ * 64 * 4);
    float* m2      = (float*)carve((size_t)BN_ * 128 * 4);
    float* m3      = (float*)carve((size_t)BN_ * 256 * 4);
    float* Ap      = (float*)carve((size_t)128 * 256 * 4);
    float* Bp      = (float*)carve((size_t)128 * 256 * 4);
    float* cvec    = (float*)carve(256 * 4);
    float* sc1     = (float*)carve(64 * 4);
    float* sh1     = (float*)carve(64 * 4);
    float* sc2     = (float*)carve(128 * 4);
    float* sh2     = (float*)carve(128 * 4);
    float* sc3     = (float*)carve(256 * 4);
    float* sh3     = (float*)carve(256 * 4);
    float* partial = (float*)carve((size_t)(BN_/GRP) * 2 * 256 * 4);
    float* gfeat   = (float*)carve((size_t)B_ * 448 * 4);

    knn_kernel<<<BN_/256, 256, 0, stream>>>(points, src);

    run_layer(points, IN_, 64,  W1, b1, g1, be1, nullptr, nullptr,
              Pb, Qb, Ap, Bp, cvec, src, m1, partial, sc1, sh1, stream);
    run_layer(m1, 64, 128, W2, b2, g2, be2, sc1, sh1,
              Pb, Qb, Ap, Bp, cvec, src, m2, partial, sc2, sh2, stream);
    run_layer(m2, 128, 256, W3, b3, g3, be3, sc2, sh2,
              Pb, Qb, Ap, Bp, cvec, src, m3, partial, sc3, sh3, stream);

    batchmax_kernel<<<dim3(B_, 1), 256, 0, stream>>>(m1, sc1, sh1, gfeat, 64, 0);
    batchmax_kernel<<<dim3(B_, 2), 256, 0, stream>>>(m2, sc2, sh2, gfeat, 128, 64);
    batchmax_kernel<<<dim3(B_, 4), 256, 0, stream>>>(m3, sc3, sh3, gfeat, 256, 192);

    final_kernel<<<1, 512, 0, stream>>>(gfeat, Wf1, bf1, gf, bef, Wf2, bf2, out);
}

// Round 3
// 599.384 us; speedup vs baseline: 1.8202x; 1.8202x over previous
//
#include <hip/hip_runtime.h>
#include <math.h>

#define B_ 8
#define N_ 2048
#define K_ 8
#define IN_ 5
#define BN_ (B_*N_)
#define NEDGE_ (BN_*K_)
#define GRP 8
#define SEG_ 16
#define CSEG_ (N_/SEG_)   // 128 candidates per segment

// ordered-float: monotone map f32 -> u32 (handles negatives from fp cancellation)
__device__ inline unsigned int ord_f32(float f) {
    unsigned int u = __float_as_uint(f);
    return (u & 0x80000000u) ? ~u : (u | 0x80000000u);
}

// ---------------- kNN phase 1: per-segment top-8 (u64 keys), high parallelism ----------------
__global__ __launch_bounds__(256) void knn_part(const float* __restrict__ points,
                                                unsigned long long* __restrict__ part) {
    int tid = threadIdx.x;
    int q = blockIdx.x * 256 + tid;     // each block stays within one batch (2048 % 256 == 0)
    int b = q / N_;
    int n = q % N_;
    int seg = blockIdx.y;
    const float* pb = points + (size_t)b * N_ * IN_;

    __shared__ float sp[CSEG_][4];
    if (tid < CSEG_) {
        int j = seg * CSEG_ + tid;
        float x = pb[(size_t)j*IN_+0], y = pb[(size_t)j*IN_+1], z = pb[(size_t)j*IN_+2];
        sp[tid][0] = x; sp[tid][1] = y; sp[tid][2] = z; sp[tid][3] = x*x + y*y + z*z;
    }
    float qx = pb[(size_t)n*IN_+0], qy = pb[(size_t)n*IN_+1], qz = pb[(size_t)n*IN_+2];
    float qsq = qx*qx + qy*qy + qz*qz;
    __syncthreads();

    unsigned long long best[K_];
#pragma unroll
    for (int k = 0; k < K_; ++k) best[k] = ~0ull;

    int jbase = seg * CSEG_;
    for (int jj = 0; jj < CSEG_; ++jj) {
        float d = qsq + sp[jj][3] - 2.0f*(qx*sp[jj][0] + qy*sp[jj][1] + qz*sp[jj][2]);
        int jg = jbase + jj;
        if (jg == n) continue;          // self-exclusion (diverges for <=1 lane)
        unsigned long long key = ((unsigned long long)ord_f32(d) << 32) | (unsigned int)jg;
        if (key < best[K_-1]) {
            unsigned long long cur = key;
#pragma unroll
            for (int p = 0; p < K_; ++p) {
                unsigned long long lo = best[p] < cur ? best[p] : cur;
                unsigned long long hi = best[p] < cur ? cur : best[p];
                best[p] = lo; cur = hi;
            }
        }
    }
    unsigned long long* op = part + ((size_t)seg * BN_ + q) * K_;
#pragma unroll
    for (int k = 0; k < K_; ++k) op[k] = best[k];
}

// ---------------- kNN phase 2: merge SEG_ sorted 8-lists -> global top-8 ----------------
__global__ __launch_bounds__(128) void knn_merge(const unsigned long long* __restrict__ part,
                                                 int* __restrict__ src) {
    int q = blockIdx.x * 128 + threadIdx.x;
    int b = q / N_;
    unsigned long long best[K_];
#pragma unroll
    for (int k = 0; k < K_; ++k) best[k] = ~0ull;
    for (int s = 0; s < SEG_; ++s) {
        const unsigned long long* lp = part + ((size_t)s * BN_ + q) * K_;
#pragma unroll
        for (int k = 0; k < K_; ++k) {
            unsigned long long key = lp[k];
            if (key >= best[K_-1]) break;   // list sorted ascending -> rest are larger
            unsigned long long cur = key;
#pragma unroll
            for (int p = 0; p < K_; ++p) {
                unsigned long long lo = best[p] < cur ? best[p] : cur;
                unsigned long long hi = best[p] < cur ? cur : best[p];
                best[p] = lo; cur = hi;
            }
        }
    }
#pragma unroll
    for (int k = 0; k < K_; ++k)
        src[(size_t)q*K_ + k] = b*N_ + (int)(best[k] & 0xFFFFFFFFu);
}

// ---------------- weight prep: fold previous-layer BN affine into W ----------------
// A' = s .* (W_top - W_bot), B' = s .* W_bot
__global__ void prep_AB(const float* __restrict__ W, const float* __restrict__ scale,
                        float* __restrict__ Ap, float* __restrict__ Bp, int Cin, int Cout) {
    int idx = blockIdx.x * 256 + threadIdx.x;
    if (idx >= Cin*Cout) return;
    int d = idx / Cout;
    float s = scale ? scale[d] : 1.0f;
    float wt = W[idx];
    float wb = W[(size_t)Cin*Cout + idx];
    Ap[idx] = s * (wt - wb);
    Bp[idx] = s * wb;
}

// c' = b + shift @ W_top
__global__ void prep_c(const float* __restrict__ W, const float* __restrict__ shift,
                       const float* __restrict__ bias, float* __restrict__ cvec,
                       int Cin, int Cout) {
    int c = blockIdx.x * 64 + threadIdx.x;
    if (c >= Cout) return;
    float acc = bias[c];
    if (shift)
        for (int d = 0; d < Cin; ++d) acc += shift[d] * W[(size_t)d*Cout + c];
    cvec[c] = acc;
}

// ---------------- fp32 tiled GEMM: C[MxN] = A[MxK] @ B[KxN], M%64==0, N%64==0 ----------------
__global__ __launch_bounds__(256) void sgemm64(const float* __restrict__ A, const float* __restrict__ B,
                                               float* __restrict__ C, int M, int N, int K) {
    __shared__ float As[16][68];
    __shared__ float Bs[16][68];
    int bm = blockIdx.y * 64, bn = blockIdx.x * 64;
    int tid = threadIdx.x;
    int tm = (tid / 16) * 4;
    int tn = (tid % 16) * 4;
    float acc[4][4] = {};
    for (int k0 = 0; k0 < K; k0 += 16) {
        for (int e = tid; e < 64*16; e += 256) {
            int row = e >> 4, kk = e & 15;
            As[kk][row] = (k0+kk < K) ? A[(size_t)(bm+row)*K + k0+kk] : 0.0f;
        }
        for (int e = tid; e < 16*64; e += 256) {
            int kk = e >> 6, col = e & 63;
            Bs[kk][col] = (k0+kk < K) ? B[(size_t)(k0+kk)*N + bn+col] : 0.0f;
        }
        __syncthreads();
#pragma unroll
        for (int kk = 0; kk < 16; ++kk) {
            float4 a4 = *reinterpret_cast<const float4*>(&As[kk][tm]);
            float4 b4 = *reinterpret_cast<const float4*>(&Bs[kk][tn]);
            float av[4] = {a4.x, a4.y, a4.z, a4.w};
            float bv[4] = {b4.x, b4.y, b4.z, b4.w};
#pragma unroll
            for (int i = 0; i < 4; ++i)
#pragma unroll
                for (int j = 0; j < 4; ++j) acc[i][j] += av[i]*bv[j];
        }
        __syncthreads();
    }
#pragma unroll
    for (int i = 0; i < 4; ++i)
#pragma unroll
        for (int j = 0; j < 4; ++j)
            C[(size_t)(bm+tm+i)*N + bn+tn+j] = acc[i][j];
}

// ---------------- edge combine: h = P[dst] + Q[src] + c ; lrelu; per-dst max; BN partials ----------------
__global__ void combine_kernel(const float* __restrict__ P, const float* __restrict__ Q,
                               const float* __restrict__ cvec, const int* __restrict__ src,
                               float* __restrict__ m_out, float* __restrict__ partial, int C) {
    int c = threadIdx.x;                 // blockDim.x == C
    int i0 = blockIdx.x * GRP;
    float cv = cvec[c];
    float sum = 0.f, ssq = 0.f;
    for (int g = 0; g < GRP; ++g) {
        int i = i0 + g;
        float p = P[(size_t)i*C + c] + cv;
        float mx = -INFINITY;
#pragma unroll
        for (int k = 0; k < K_; ++k) {
            int s = src[(size_t)i*K_ + k];
            float h = p + Q[(size_t)s*C + c];
            float l = (h >= 0.f) ? h : 0.2f*h;
            sum += l; ssq += l*l;
            mx = fmaxf(mx, l);
        }
        m_out[(size_t)i*C + c] = mx;     // pre-affine max of lrelu
    }
    partial[(size_t)blockIdx.x*2*C + c]     = sum;
    partial[(size_t)blockIdx.x*2*C + C + c] = ssq;
}

// ---------------- BN stats reduce -> scale/shift (deterministic tree) ----------------
__global__ __launch_bounds__(256) void reduce_kernel(const float* __restrict__ partial, int nblocks, int C,
                              const float* __restrict__ g, const float* __restrict__ be,
                              float* __restrict__ scale, float* __restrict__ shift) {
    int c = blockIdx.x;
    float s0 = 0.f, s1 = 0.f;
    for (int blk = threadIdx.x; blk < nblocks; blk += 256) {
        s0 += partial[(size_t)blk*2*C + c];
        s1 += partial[(size_t)blk*2*C + C + c];
    }
    __shared__ float l0[256], l1[256];
    l0[threadIdx.x] = s0; l1[threadIdx.x] = s1;
    __syncthreads();
    for (int off = 128; off > 0; off >>= 1) {
        if (threadIdx.x < off) {
            l0[threadIdx.x] += l0[threadIdx.x + off];
            l1[threadIdx.x] += l1[threadIdx.x + off];
        }
        __syncthreads();
    }
    if (threadIdx.x == 0) {
        float mean = l0[0] / (float)NEDGE_;
        float var  = l1[0] / (float)NEDGE_ - mean*mean;
        float sc = g[c] * rsqrtf(var + 1e-5f);
        scale[c] = sc;
        shift[c] = be[c] - mean*sc;
    }
}

// ---------------- per-batch global max over N points (+apply BN affine) ----------------
__global__ __launch_bounds__(256) void batchmax_kernel(const float* __restrict__ m, const float* __restrict__ scale,
                                const float* __restrict__ shift, float* __restrict__ gfeat,
                                int C, int coff) {
    int b = blockIdx.x;
    int cl = threadIdx.x & 63;
    int c = blockIdx.y * 64 + cl;
    int stripe = threadIdx.x >> 6;  // 0..3
    const float* mb = m + (size_t)b*N_*C + c;
    float mx = -INFINITY;
    for (int n = stripe; n < N_; n += 4)
        mx = fmaxf(mx, mb[(size_t)n*C]);
    __shared__ float red[256];
    red[threadIdx.x] = mx;
    __syncthreads();
    if (stripe == 0) {
        float v = fmaxf(fmaxf(red[cl], red[cl+64]), fmaxf(red[cl+128], red[cl+192]));
        gfeat[b*448 + coff + c] = scale[c]*v + shift[c];
    }
}

// ---------------- final head: gfeat@Wf1 + lrelu + BN(8 rows) + @Wf2 ----------------
__global__ __launch_bounds__(512) void final_kernel(const float* __restrict__ gfeat,
                             const float* __restrict__ Wf1, const float* __restrict__ bf1,
                             const float* __restrict__ gf, const float* __restrict__ bef,
                             const float* __restrict__ Wf2, const float* __restrict__ bf2,
                             float* __restrict__ out) {
    __shared__ float gf_s[B_][448];
    __shared__ float h_s[B_][512];
    int t = threadIdx.x;
    for (int e = t; e < B_*448; e += 512) gf_s[e/448][e%448] = gfeat[e];
    __syncthreads();
    float acc[B_];
#pragma unroll
    for (int r = 0; r < B_; ++r) acc[r] = bf1[t];
    for (int d = 0; d < 448; ++d) {
        float w = Wf1[(size_t)d*512 + t];
#pragma unroll
        for (int r = 0; r < B_; ++r) acc[r] += gf_s[r][d] * w;
    }
#pragma unroll
    for (int r = 0; r < B_; ++r) { float v = acc[r]; acc[r] = (v >= 0.f) ? v : 0.2f*v; }
    float mean = 0.f;
#pragma unroll
    for (int r = 0; r < B_; ++r) mean += acc[r];
    mean *= (1.0f/B_);
    float var = 0.f;
#pragma unroll
    for (int r = 0; r < B_; ++r) { float dd = acc[r] - mean; var += dd*dd; }
    var *= (1.0f/B_);
    float sc = gf[t] * rsqrtf(var + 1e-5f);
    float sh = bef[t] - mean*sc;
#pragma unroll
    for (int r = 0; r < B_; ++r) h_s[r][t] = acc[r]*sc + sh;
    __syncthreads();
    for (int e = t; e < B_*128; e += 512) {
        int r = e >> 7, c = e & 127;
        float a = bf2[c];
        for (int d = 0; d < 512; ++d) a += h_s[r][d] * Wf2[(size_t)d*128 + c];
        out[e] = a;
    }
}

// ---------------- host side ----------------
static void run_layer(const float* X, int Cin, int Cout,
                      const float* W, const float* b, const float* g, const float* be,
                      const float* scale_in, const float* shift_in,
                      float* Pb, float* Qb, float* Ap, float* Bp, float* cvec,
                      const int* src, float* m_out, float* partial,
                      float* scale_out, float* shift_out, hipStream_t stream) {
    int nAB = Cin * Cout;
    prep_AB<<<(nAB + 255)/256, 256, 0, stream>>>(W, scale_in, Ap, Bp, Cin, Cout);
    prep_c<<<(Cout + 63)/64, 64, 0, stream>>>(W, shift_in, b, cvec, Cin, Cout);
    sgemm64<<<dim3(Cout/64, BN_/64), 256, 0, stream>>>(X, Ap, Pb, BN_, Cout, Cin);
    sgemm64<<<dim3(Cout/64, BN_/64), 256, 0, stream>>>(X, Bp, Qb, BN_, Cout, Cin);
    combine_kernel<<<BN_/GRP, Cout, 0, stream>>>(Pb, Qb, cvec, src, m_out, partial, Cout);
    reduce_kernel<<<Cout, 256, 0, stream>>>(partial, BN_/GRP, Cout, g, be, scale_out, shift_out);
}

extern "C" void kernel_launch(void* const* d_in, const int* in_sizes, int n_in,
                              void* d_out, int out_size, void* d_ws, size_t ws_size,
                              hipStream_t stream) {
    (void)in_sizes; (void)n_in; (void)out_size; (void)ws_size;
    const float* points = (const float*)d_in[0];
    const float* W1 = (const float*)d_in[1];  const float* b1 = (const float*)d_in[2];
    const float* g1 = (const float*)d_in[3];  const float* be1 = (const float*)d_in[4];
    const float* W2 = (const float*)d_in[5];  const float* b2 = (const float*)d_in[6];
    const float* g2 = (const float*)d_in[7];  const float* be2 = (const float*)d_in[8];
    const float* W3 = (const float*)d_in[9];  const float* b3 = (const float*)d_in[10];
    const float* g3 = (const float*)d_in[11]; const float* be3 = (const float*)d_in[12];
    const float* Wf1 = (const float*)d_in[13]; const float* bf1 = (const float*)d_in[14];
    const float* gf = (const float*)d_in[15];  const float* bef = (const float*)d_in[16];
    const float* Wf2 = (const float*)d_in[17]; const float* bf2 = (const float*)d_in[18];
    float* out = (float*)d_out;

    size_t off = 0;
    char* base = (char*)d_ws;
    auto carve = [&](size_t bytes) -> void* {
        void* p = base + off;
        off += (bytes + 255) & ~(size_t)255;
        return p;
    };
    int*   src     = (int*)  carve((size_t)NEDGE_ * 4);
    float* Pb      = (float*)carve((size_t)BN_ * 256 * 4);
    float* Qb      = (float*)carve((size_t)BN_ * 256 * 4);
    float* m1      = (float*)carve((size_t)BN_ * 64 * 4);
    float* m2      = (float*)carve((size_t)BN_ * 128 * 4);
    float* m3      = (float*)carve((size_t)BN_ * 256 * 4);
    float* Ap      = (float*)carve((size_t)128 * 256 * 4);
    float* Bp      = (float*)carve((size_t)128 * 256 * 4);
    float* cvec    = (float*)carve(256 * 4);
    float* sc1     = (float*)carve(64 * 4);
    float* sh1     = (float*)carve(64 * 4);
    float* sc2     = (float*)carve(128 * 4);
    float* sh2     = (float*)carve(128 * 4);
    float* sc3     = (float*)carve(256 * 4);
    float* sh3     = (float*)carve(256 * 4);
    float* partial = (float*)carve((size_t)(BN_/GRP) * 2 * 256 * 4);
    float* gfeat   = (float*)carve((size_t)B_ * 448 * 4);

    // kNN: phase-1 partials overlay Pb (16 MB, exactly SEG_*BN_*8*8B); Pb is
    // dead until the first sgemm64, which runs after knn_merge on the same stream.
    unsigned long long* part = (unsigned long long*)Pb;
    knn_part<<<dim3(BN_/256, SEG_), 256, 0, stream>>>(points, part);
    knn_merge<<<BN_/128, 128, 0, stream>>>(part, src);

    run_layer(points, IN_, 64,  W1, b1, g1, be1, nullptr, nullptr,
              Pb, Qb, Ap, Bp, cvec, src, m1, partial, sc1, sh1, stream);
    run_layer(m1, 64, 128, W2, b2, g2, be2, sc1, sh1,
              Pb, Qb, Ap, Bp, cvec, src, m2, partial, sc2, sh2, stream);
    run_layer(m2, 128, 256, W3, b3, g3, be3, sc2, sh2,
              Pb, Qb, Ap, Bp, cvec, src, m3, partial, sc3, sh3, stream);

    batchmax_kernel<<<dim3(B_, 1), 256, 0, stream>>>(m1, sc1, sh1, gfeat, 64, 0);
    batchmax_kernel<<<dim3(B_, 2), 256, 0, stream>>>(m2, sc2, sh2, gfeat, 128, 64);
    batchmax_kernel<<<dim3(B_, 4), 256, 0, stream>>>(m3, sc3, sh3, gfeat, 256, 192);

    final_kernel<<<1, 512, 0, stream>>>(gfeat, Wf1, bf1, gf, bef, Wf2, bf2, out);
}

// Round 4
// 360.853 us; speedup vs baseline: 3.0234x; 1.6610x over previous
//
#include <hip/hip_runtime.h>
#include <math.h>

#define B_ 8
#define N_ 2048
#define K_ 8
#define IN_ 5
#define BN_ (B_*N_)
#define NEDGE_ (BN_*K_)
#define GRP 8
#define SEG_ 32
#define CSEG_ (N_/SEG_)   // 64 candidates per segment
#define CHUNKS_ (N_/GRP)  // 256 combine-blocks per batch

// ordered-float: monotone map f32 -> u32 (handles negatives from fp cancellation)
__device__ inline unsigned int ord_f32(float f) {
    unsigned int u = __float_as_uint(f);
    return (u & 0x80000000u) ? ~u : (u | 0x80000000u);
}

// ---------------- kNN phase 1: per-segment top-8 (u64 keys), high parallelism ----------------
__global__ __launch_bounds__(256) void knn_part(const float* __restrict__ points,
                                                unsigned long long* __restrict__ part) {
    int tid = threadIdx.x;
    int q = blockIdx.x * 256 + tid;     // each block stays within one batch (2048 % 256 == 0)
    int b = q / N_;
    int n = q % N_;
    int seg = blockIdx.y;
    const float* pb = points + (size_t)b * N_ * IN_;

    __shared__ float sp[CSEG_][4];
    if (tid < CSEG_) {
        int j = seg * CSEG_ + tid;
        float x = pb[(size_t)j*IN_+0], y = pb[(size_t)j*IN_+1], z = pb[(size_t)j*IN_+2];
        sp[tid][0] = x; sp[tid][1] = y; sp[tid][2] = z; sp[tid][3] = x*x + y*y + z*z;
    }
    float qx = pb[(size_t)n*IN_+0], qy = pb[(size_t)n*IN_+1], qz = pb[(size_t)n*IN_+2];
    float qsq = qx*qx + qy*qy + qz*qz;
    __syncthreads();

    unsigned long long best[K_];
#pragma unroll
    for (int k = 0; k < K_; ++k) best[k] = ~0ull;

    int jbase = seg * CSEG_;
    for (int jj = 0; jj < CSEG_; ++jj) {
        float d = qsq + sp[jj][3] - 2.0f*(qx*sp[jj][0] + qy*sp[jj][1] + qz*sp[jj][2]);
        int jg = jbase + jj;
        if (jg == n) continue;          // self-exclusion (diverges for <=1 lane)
        unsigned long long key = ((unsigned long long)ord_f32(d) << 32) | (unsigned int)jg;
        if (key < best[K_-1]) {
            unsigned long long cur = key;
#pragma unroll
            for (int p = 0; p < K_; ++p) {
                unsigned long long lo = best[p] < cur ? best[p] : cur;
                unsigned long long hi = best[p] < cur ? cur : best[p];
                best[p] = lo; cur = hi;
            }
        }
    }
    unsigned long long* op = part + ((size_t)seg * BN_ + q) * K_;
#pragma unroll
    for (int k = 0; k < K_; ++k) op[k] = best[k];
}

// ---------------- kNN phase 2: merge SEG_ sorted 8-lists -> global top-8 ----------------
__global__ __launch_bounds__(128) void knn_merge(const unsigned long long* __restrict__ part,
                                                 int* __restrict__ src) {
    int q = blockIdx.x * 128 + threadIdx.x;
    int b = q / N_;
    unsigned long long best[K_];
#pragma unroll
    for (int k = 0; k < K_; ++k) best[k] = ~0ull;
    for (int s = 0; s < SEG_; ++s) {
        const unsigned long long* lp = part + ((size_t)s * BN_ + q) * K_;
#pragma unroll
        for (int k = 0; k < K_; ++k) {
            unsigned long long key = lp[k];
            if (key >= best[K_-1]) break;   // list sorted ascending -> rest are larger
            unsigned long long cur = key;
#pragma unroll
            for (int p = 0; p < K_; ++p) {
                unsigned long long lo = best[p] < cur ? best[p] : cur;
                unsigned long long hi = best[p] < cur ? cur : best[p];
                best[p] = lo; cur = hi;
            }
        }
    }
#pragma unroll
    for (int k = 0; k < K_; ++k)
        src[(size_t)q*K_ + k] = b*N_ + (int)(best[k] & 0xFFFFFFFFu);
}

// ---------------- weight prep: fold previous-layer BN affine into W ----------------
// A' = s .* (W_top - W_bot), B' = s .* W_bot
__global__ void prep_AB(const float* __restrict__ W, const float* __restrict__ scale,
                        float* __restrict__ Ap, float* __restrict__ Bp, int Cin, int Cout) {
    int idx = blockIdx.x * 256 + threadIdx.x;
    if (idx >= Cin*Cout) return;
    int d = idx / Cout;
    float s = scale ? scale[d] : 1.0f;
    float wt = W[idx];
    float wb = W[(size_t)Cin*Cout + idx];
    Ap[idx] = s * (wt - wb);
    Bp[idx] = s * wb;
}

// c' = b + shift @ W_top
__global__ void prep_c(const float* __restrict__ W, const float* __restrict__ shift,
                       const float* __restrict__ bias, float* __restrict__ cvec,
                       int Cin, int Cout) {
    int c = blockIdx.x * 64 + threadIdx.x;
    if (c >= Cout) return;
    float acc = bias[c];
    if (shift)
        for (int d = 0; d < Cin; ++d) acc += shift[d] * W[(size_t)d*Cout + c];
    cvec[c] = acc;
}

// ---------------- fp32 tiled GEMM: C[MxN] = A[MxK] @ B[KxN], M%64==0, N%64==0 ----------------
__global__ __launch_bounds__(256) void sgemm64(const float* __restrict__ A, const float* __restrict__ B,
                                               float* __restrict__ C, int M, int N, int K) {
    __shared__ float As[16][68];
    __shared__ float Bs[16][68];
    int bm = blockIdx.y * 64, bn = blockIdx.x * 64;
    int tid = threadIdx.x;
    int tm = (tid / 16) * 4;
    int tn = (tid % 16) * 4;
    float acc[4][4] = {};
    for (int k0 = 0; k0 < K; k0 += 16) {
        for (int e = tid; e < 64*16; e += 256) {
            int row = e >> 4, kk = e & 15;
            As[kk][row] = (k0+kk < K) ? A[(size_t)(bm+row)*K + k0+kk] : 0.0f;
        }
        for (int e = tid; e < 16*64; e += 256) {
            int kk = e >> 6, col = e & 63;
            Bs[kk][col] = (k0+kk < K) ? B[(size_t)(k0+kk)*N + bn+col] : 0.0f;
        }
        __syncthreads();
#pragma unroll
        for (int kk = 0; kk < 16; ++kk) {
            float4 a4 = *reinterpret_cast<const float4*>(&As[kk][tm]);
            float4 b4 = *reinterpret_cast<const float4*>(&Bs[kk][tn]);
            float av[4] = {a4.x, a4.y, a4.z, a4.w};
            float bv[4] = {b4.x, b4.y, b4.z, b4.w};
#pragma unroll
            for (int i = 0; i < 4; ++i)
#pragma unroll
                for (int j = 0; j < 4; ++j) acc[i][j] += av[i]*bv[j];
        }
        __syncthreads();
    }
#pragma unroll
    for (int i = 0; i < 4; ++i)
#pragma unroll
        for (int j = 0; j < 4; ++j)
            C[(size_t)(bm+tm+i)*N + bn+tn+j] = acc[i][j];
}

// ---------------- edge combine: h = P[dst] + Q[src] + c ; lrelu; per-dst max; BN partials;
//                  per-block (8-point) partial max for the global max-pool ----------------
__global__ void combine_kernel(const float* __restrict__ P, const float* __restrict__ Q,
                               const float* __restrict__ cvec, const int* __restrict__ src,
                               float* __restrict__ m_out, float* __restrict__ partial,
                               float* __restrict__ gpart, int C) {
    int c = threadIdx.x;                 // blockDim.x == C
    int i0 = blockIdx.x * GRP;
    float cv = cvec[c];
    float sum = 0.f, ssq = 0.f;
    float bmx = -INFINITY;
    for (int g = 0; g < GRP; ++g) {
        int i = i0 + g;
        float p = P[(size_t)i*C + c] + cv;
        float mx = -INFINITY;
#pragma unroll
        for (int k = 0; k < K_; ++k) {
            int s = src[(size_t)i*K_ + k];
            float h = p + Q[(size_t)s*C + c];
            float l = (h >= 0.f) ? h : 0.2f*h;
            sum += l; ssq += l*l;
            mx = fmaxf(mx, l);
        }
        if (m_out) m_out[(size_t)i*C + c] = mx;   // pre-affine max of lrelu (next layer's input)
        bmx = fmaxf(bmx, mx);
    }
    gpart[(size_t)blockIdx.x*C + c] = bmx;        // per-block partial for global max-pool
    partial[(size_t)blockIdx.x*2*C + c]     = sum;
    partial[(size_t)blockIdx.x*2*C + C + c] = ssq;
}

// ---------------- BN stats reduce -> scale/shift (deterministic tree) ----------------
__global__ __launch_bounds__(256) void reduce_kernel(const float* __restrict__ partial, int nblocks, int C,
                              const float* __restrict__ g, const float* __restrict__ be,
                              float* __restrict__ scale, float* __restrict__ shift) {
    int c = blockIdx.x;
    float s0 = 0.f, s1 = 0.f;
    for (int blk = threadIdx.x; blk < nblocks; blk += 256) {
        s0 += partial[(size_t)blk*2*C + c];
        s1 += partial[(size_t)blk*2*C + C + c];
    }
    __shared__ float l0[256], l1[256];
    l0[threadIdx.x] = s0; l1[threadIdx.x] = s1;
    __syncthreads();
    for (int off = 128; off > 0; off >>= 1) {
        if (threadIdx.x < off) {
            l0[threadIdx.x] += l0[threadIdx.x + off];
            l1[threadIdx.x] += l1[threadIdx.x + off];
        }
        __syncthreads();
    }
    if (threadIdx.x == 0) {
        float mean = l0[0] / (float)NEDGE_;
        float var  = l1[0] / (float)NEDGE_ - mean*mean;
        float sc = g[c] * rsqrtf(var + 1e-5f);
        scale[c] = sc;
        shift[c] = be[c] - mean*sc;
    }
}

// ---------------- fused global max-pool finalize: reduce CHUNKS_ partials, apply BN affine ----------------
// grid (B_, 7): blockIdx.y -> 64-channel group within the 448-wide concat
__global__ __launch_bounds__(1024) void gmax_finalize(
        const float* __restrict__ gp1, const float* __restrict__ gp2, const float* __restrict__ gp3,
        const float* __restrict__ sc1, const float* __restrict__ sh1,
        const float* __restrict__ sc2, const float* __restrict__ sh2,
        const float* __restrict__ sc3, const float* __restrict__ sh3,
        float* __restrict__ gfeat) {
    int b = blockIdx.x, grp = blockIdx.y;
    const float *gp, *sc, *sh; int C, c0, coff;
    if (grp == 0)      { gp = gp1; sc = sc1; sh = sh1; C = 64;  c0 = 0;            coff = 0;   }
    else if (grp <= 2) { gp = gp2; sc = sc2; sh = sh2; C = 128; c0 = (grp-1)*64;   coff = 64;  }
    else               { gp = gp3; sc = sc3; sh = sh3; C = 256; c0 = (grp-3)*64;   coff = 192; }
    int cl = threadIdx.x & 63;
    int stripe = threadIdx.x >> 6;   // 0..15
    int c = c0 + cl;
    float mx = -INFINITY;
    for (int ch = stripe; ch < CHUNKS_; ch += 16)
        mx = fmaxf(mx, gp[((size_t)b*CHUNKS_ + ch)*C + c]);
    __shared__ float red[16][64];
    red[stripe][cl] = mx;
    __syncthreads();
    for (int off = 8; off > 0; off >>= 1) {
        if (stripe < off) red[stripe][cl] = fmaxf(red[stripe][cl], red[stripe+off][cl]);
        __syncthreads();
    }
    if (stripe == 0)
        gfeat[b*448 + coff + c] = sc[c]*red[0][cl] + sh[c];
}

// ---------------- final head: gfeat@Wf1 + lrelu + BN(8 rows) + @Wf2 ----------------
__global__ __launch_bounds__(512) void final_kernel(const float* __restrict__ gfeat,
                             const float* __restrict__ Wf1, const float* __restrict__ bf1,
                             const float* __restrict__ gf, const float* __restrict__ bef,
                             const float* __restrict__ Wf2, const float* __restrict__ bf2,
                             float* __restrict__ out) {
    __shared__ float gf_s[B_][448];
    __shared__ float h_s[B_][512];
    int t = threadIdx.x;
    for (int e = t; e < B_*448; e += 512) gf_s[e/448][e%448] = gfeat[e];
    __syncthreads();
    float acc[B_];
#pragma unroll
    for (int r = 0; r < B_; ++r) acc[r] = bf1[t];
    for (int d = 0; d < 448; ++d) {
        float w = Wf1[(size_t)d*512 + t];
#pragma unroll
        for (int r = 0; r < B_; ++r) acc[r] += gf_s[r][d] * w;
    }
#pragma unroll
    for (int r = 0; r < B_; ++r) { float v = acc[r]; acc[r] = (v >= 0.f) ? v : 0.2f*v; }
    float mean = 0.f;
#pragma unroll
    for (int r = 0; r < B_; ++r) mean += acc[r];
    mean *= (1.0f/B_);
    float var = 0.f;
#pragma unroll
    for (int r = 0; r < B_; ++r) { float dd = acc[r] - mean; var += dd*dd; }
    var *= (1.0f/B_);
    float sc = gf[t] * rsqrtf(var + 1e-5f);
    float sh = bef[t] - mean*sc;
#pragma unroll
    for (int r = 0; r < B_; ++r) h_s[r][t] = acc[r]*sc + sh;
    __syncthreads();
    for (int e = t; e < B_*128; e += 512) {
        int r = e >> 7, c = e & 127;
        float a = bf2[c];
        for (int d = 0; d < 512; ++d) a += h_s[r][d] * Wf2[(size_t)d*128 + c];
        out[e] = a;
    }
}

// ---------------- host side ----------------
static void run_layer(const float* X, int Cin, int Cout,
                      const float* W, const float* b, const float* g, const float* be,
                      const float* scale_in, const float* shift_in,
                      float* Pb, float* Qb, float* Ap, float* Bp, float* cvec,
                      const int* src, float* m_out, float* partial, float* gpart,
                      float* scale_out, float* shift_out, hipStream_t stream) {
    int nAB = Cin * Cout;
    prep_AB<<<(nAB + 255)/256, 256, 0, stream>>>(W, scale_in, Ap, Bp, Cin, Cout);
    prep_c<<<(Cout + 63)/64, 64, 0, stream>>>(W, shift_in, b, cvec, Cin, Cout);
    sgemm64<<<dim3(Cout/64, BN_/64), 256, 0, stream>>>(X, Ap, Pb, BN_, Cout, Cin);
    sgemm64<<<dim3(Cout/64, BN_/64), 256, 0, stream>>>(X, Bp, Qb, BN_, Cout, Cin);
    combine_kernel<<<BN_/GRP, Cout, 0, stream>>>(Pb, Qb, cvec, src, m_out, partial, gpart, Cout);
    reduce_kernel<<<Cout, 256, 0, stream>>>(partial, BN_/GRP, Cout, g, be, scale_out, shift_out);
}

extern "C" void kernel_launch(void* const* d_in, const int* in_sizes, int n_in,
                              void* d_out, int out_size, void* d_ws, size_t ws_size,
                              hipStream_t stream) {
    (void)in_sizes; (void)n_in; (void)out_size; (void)ws_size;
    const float* points = (const float*)d_in[0];
    const float* W1 = (const float*)d_in[1];  const float* b1 = (const float*)d_in[2];
    const float* g1 = (const float*)d_in[3];  const float* be1 = (const float*)d_in[4];
    const float* W2 = (const float*)d_in[5];  const float* b2 = (const float*)d_in[6];
    const float* g2 = (const float*)d_in[7];  const float* be2 = (const float*)d_in[8];
    const float* W3 = (const float*)d_in[9];  const float* b3 = (const float*)d_in[10];
    const float* g3 = (const float*)d_in[11]; const float* be3 = (const float*)d_in[12];
    const float* Wf1 = (const float*)d_in[13]; const float* bf1 = (const float*)d_in[14];
    const float* gf = (const float*)d_in[15];  const float* bef = (const float*)d_in[16];
    const float* Wf2 = (const float*)d_in[17]; const float* bf2 = (const float*)d_in[18];
    float* out = (float*)d_out;

    size_t off = 0;
    char* base = (char*)d_ws;
    auto carve = [&](size_t bytes) -> void* {
        void* p = base + off;
        off += (bytes + 255) & ~(size_t)255;
        return p;
    };
    int*   src     = (int*)  carve((size_t)NEDGE_ * 4);
    float* Pb      = (float*)carve((size_t)BN_ * 256 * 4);   // NOTE: Pb+Qb contiguous (each 16MB,
    float* Qb      = (float*)carve((size_t)BN_ * 256 * 4);   // 256-aligned) -> knn part overlay = 32MB
    float* m1      = (float*)carve((size_t)BN_ * 64 * 4);
    float* m2      = (float*)carve((size_t)BN_ * 128 * 4);
    float* gp1     = (float*)carve((size_t)(BN_/GRP) * 64 * 4);
    float* gp2     = (float*)carve((size_t)(BN_/GRP) * 128 * 4);
    float* gp3     = (float*)carve((size_t)(BN_/GRP) * 256 * 4);
    float* Ap      = (float*)carve((size_t)128 * 256 * 4);
    float* Bp      = (float*)carve((size_t)128 * 256 * 4);
    float* cvec    = (float*)carve(256 * 4);
    float* sc1     = (float*)carve(64 * 4);
    float* sh1     = (float*)carve(64 * 4);
    float* sc2     = (float*)carve(128 * 4);
    float* sh2     = (float*)carve(128 * 4);
    float* sc3     = (float*)carve(256 * 4);
    float* sh3     = (float*)carve(256 * 4);
    float* partial = (float*)carve((size_t)(BN_/GRP) * 2 * 256 * 4);
    float* gfeat   = (float*)carve((size_t)B_ * 448 * 4);

    // kNN: phase-1 partials (SEG_*BN_*K_*8B = 32MB) overlay Pb+Qb, dead until first sgemm64.
    unsigned long long* part = (unsigned long long*)Pb;
    knn_part<<<dim3(BN_/256, SEG_), 256, 0, stream>>>(points, part);
    knn_merge<<<BN_/128, 128, 0, stream>>>(part, src);

    run_layer(points, IN_, 64,  W1, b1, g1, be1, nullptr, nullptr,
              Pb, Qb, Ap, Bp, cvec, src, m1, partial, gp1, sc1, sh1, stream);
    run_layer(m1, 64, 128, W2, b2, g2, be2, sc1, sh1,
              Pb, Qb, Ap, Bp, cvec, src, m2, partial, gp2, sc2, sh2, stream);
    run_layer(m2, 128, 256, W3, b3, g3, be3, sc2, sh2,
              Pb, Qb, Ap, Bp, cvec, src, nullptr, partial, gp3, sc3, sh3, stream);

    gmax_finalize<<<dim3(B_, 7), 1024, 0, stream>>>(gp1, gp2, gp3,
                                                    sc1, sh1, sc2, sh2, sc3, sh3, gfeat);

    final_kernel<<<1, 512, 0, stream>>>(gfeat, Wf1, bf1, gf, bef, Wf2, bf2, out);
}

// Round 5
// 295.820 us; speedup vs baseline: 3.6880x; 1.2198x over previous
//
#include <hip/hip_runtime.h>
#include <math.h>

#define B_ 8
#define N_ 2048
#define K_ 8
#define IN_ 5
#define BN_ (B_*N_)
#define NEDGE_ (BN_*K_)
#define GRP 8
#define SEG_ 32
#define CSEG_ (N_/SEG_)   // 64 candidates per segment
#define CHUNKS_ (N_/GRP)  // 256 combine-blocks per batch

typedef unsigned short ushort8_ __attribute__((ext_vector_type(8)));
typedef short bf16x8_ __attribute__((ext_vector_type(8)));
typedef float f32x4_ __attribute__((ext_vector_type(4)));

// float -> bf16 (RNE), bf16 -> float
__device__ inline unsigned short f2bf(float f) {
    unsigned int u = __float_as_uint(f);
    u += 0x7fffu + ((u >> 16) & 1u);
    return (unsigned short)(u >> 16);
}
__device__ inline float bf2f(unsigned short h) {
    return __uint_as_float(((unsigned int)h) << 16);
}

// ordered-float: monotone map f32 -> u32
__device__ inline unsigned int ord_f32(float f) {
    unsigned int u = __float_as_uint(f);
    return (u & 0x80000000u) ? ~u : (u | 0x80000000u);
}

// ---------------- kNN phase 1: per-segment top-8 (u64 keys) ----------------
__global__ __launch_bounds__(256) void knn_part(const float* __restrict__ points,
                                                unsigned long long* __restrict__ part) {
    int tid = threadIdx.x;
    int q = blockIdx.x * 256 + tid;
    int b = q / N_;
    int n = q % N_;
    int seg = blockIdx.y;
    const float* pb = points + (size_t)b * N_ * IN_;

    __shared__ float sp[CSEG_][4];
    if (tid < CSEG_) {
        int j = seg * CSEG_ + tid;
        float x = pb[(size_t)j*IN_+0], y = pb[(size_t)j*IN_+1], z = pb[(size_t)j*IN_+2];
        sp[tid][0] = x; sp[tid][1] = y; sp[tid][2] = z; sp[tid][3] = x*x + y*y + z*z;
    }
    float qx = pb[(size_t)n*IN_+0], qy = pb[(size_t)n*IN_+1], qz = pb[(size_t)n*IN_+2];
    float qsq = qx*qx + qy*qy + qz*qz;
    __syncthreads();

    unsigned long long best[K_];
#pragma unroll
    for (int k = 0; k < K_; ++k) best[k] = ~0ull;

    int jbase = seg * CSEG_;
    for (int jj = 0; jj < CSEG_; ++jj) {
        float d = qsq + sp[jj][3] - 2.0f*(qx*sp[jj][0] + qy*sp[jj][1] + qz*sp[jj][2]);
        int jg = jbase + jj;
        if (jg == n) continue;
        unsigned long long key = ((unsigned long long)ord_f32(d) << 32) | (unsigned int)jg;
        if (key < best[K_-1]) {
            unsigned long long cur = key;
#pragma unroll
            for (int p = 0; p < K_; ++p) {
                unsigned long long lo = best[p] < cur ? best[p] : cur;
                unsigned long long hi = best[p] < cur ? cur : best[p];
                best[p] = lo; cur = hi;
            }
        }
    }
    unsigned long long* op = part + ((size_t)seg * BN_ + q) * K_;
#pragma unroll
    for (int k = 0; k < K_; ++k) op[k] = best[k];
}

// ---------------- kNN phase 2: merge SEG_ sorted 8-lists ----------------
__global__ __launch_bounds__(128) void knn_merge(const unsigned long long* __restrict__ part,
                                                 int* __restrict__ src) {
    int q = blockIdx.x * 128 + threadIdx.x;
    int b = q / N_;
    unsigned long long best[K_];
#pragma unroll
    for (int k = 0; k < K_; ++k) best[k] = ~0ull;
    for (int s = 0; s < SEG_; ++s) {
        const unsigned long long* lp = part + ((size_t)s * BN_ + q) * K_;
#pragma unroll
        for (int k = 0; k < K_; ++k) {
            unsigned long long key = lp[k];
            if (key >= best[K_-1]) break;
            unsigned long long cur = key;
#pragma unroll
            for (int p = 0; p < K_; ++p) {
                unsigned long long lo = best[p] < cur ? best[p] : cur;
                unsigned long long hi = best[p] < cur ? cur : best[p];
                best[p] = lo; cur = hi;
            }
        }
    }
#pragma unroll
    for (int k = 0; k < K_; ++k)
        src[(size_t)q*K_ + k] = b*N_ + (int)(best[k] & 0xFFFFFFFFu);
}

// ---------------- input cast: fp32 [M][Kin] -> split bf16 hi/lo [M][Kpad] (zero-padded) ----------------
__global__ __launch_bounds__(256) void cast_split(const float* __restrict__ X,
                                                  unsigned short* __restrict__ Xh,
                                                  unsigned short* __restrict__ Xl,
                                                  int Kin, int Kpad, int total8) {
    int t = blockIdx.x * 256 + threadIdx.x;
    if (t >= total8) return;
    int vpr = Kpad >> 3;                 // ushort8 chunks per row
    int m = t / vpr;
    int k0 = (t % vpr) * 8;
    ushort8_ vh, vl;
#pragma unroll
    for (int j = 0; j < 8; ++j) {
        int k = k0 + j;
        float v = (k < Kin) ? X[(size_t)m*Kin + k] : 0.0f;
        unsigned short h = f2bf(v);
        vh[j] = h;
        vl[j] = f2bf(v - bf2f(h));
    }
    *(ushort8_*)(Xh + (size_t)m*Kpad + k0) = vh;
    *(ushort8_*)(Xl + (size_t)m*Kpad + k0) = vl;
}

// ---------------- weight prep: transposed split-bf16 [A'|B']^T with BN fold ----------------
// W: [2Cin][C] fp32. WT row n (n<C -> A'[.][n] = s.*(Wt-Wb); n>=C -> B'[.][n-C] = s.*Wb), cols k (zero-pad to Kpad)
__global__ __launch_bounds__(256) void prep_WT(const float* __restrict__ W, const float* __restrict__ scale,
                                               unsigned short* __restrict__ WTh, unsigned short* __restrict__ WTl,
                                               int Cin, int C, int Kpad) {
    int idx = blockIdx.x * 256 + threadIdx.x;
    if (idx >= 2*C*Kpad) return;
    int n = idx / Kpad;
    int k = idx % Kpad;
    float val = 0.0f;
    if (k < Cin) {
        float s = scale ? scale[k] : 1.0f;
        if (n < C) val = s * (W[(size_t)k*C + n] - W[(size_t)(Cin+k)*C + n]);
        else       val = s * W[(size_t)(Cin+k)*C + (n - C)];
    }
    unsigned short h = f2bf(val);
    WTh[(size_t)n*Kpad + k] = h;
    WTl[(size_t)n*Kpad + k] = f2bf(val - bf2f(h));
}

// c' = b + shift @ W_top
__global__ void prep_c(const float* __restrict__ W, const float* __restrict__ shift,
                       const float* __restrict__ bias, float* __restrict__ cvec,
                       int Cin, int Cout) {
    int c = blockIdx.x * 64 + threadIdx.x;
    if (c >= Cout) return;
    float acc = bias[c];
    if (shift)
        for (int d = 0; d < Cin; ++d) acc += shift[d] * W[(size_t)d*Cout + c];
    cvec[c] = acc;
}

// ---------------- split-bf16 MFMA GEMM: PQ[M][Ntot] = X[M][K] @ WT^T, 128x128 tile, BK=32 ----------------
// C = Xh@Wh + Xh@Wl + Xl@Wh (fp32 accum) -> ~fp32 accuracy
__global__ __launch_bounds__(256) void mfma_dual(const unsigned short* __restrict__ Xh,
                                                 const unsigned short* __restrict__ Xl,
                                                 const unsigned short* __restrict__ WTh,
                                                 const unsigned short* __restrict__ WTl,
                                                 float* __restrict__ PQ, int K, int Ntot) {
    __shared__ unsigned short sXh[128*32], sXl[128*32], sWh[128*32], sWl[128*32];
    int tid = threadIdx.x, l = tid & 63, w = tid >> 6;
    int wr = w >> 1, wc = w & 1;                       // 2x2 waves -> 64x64 per wave
    int bm = blockIdx.y * 128, bn0 = blockIdx.x * 128;

    f32x4_ acc[4][4];
#pragma unroll
    for (int i = 0; i < 4; ++i)
#pragma unroll
        for (int j = 0; j < 4; ++j) acc[i][j] = (f32x4_){0.f, 0.f, 0.f, 0.f};

    for (int k0 = 0; k0 < K; k0 += 32) {
#pragma unroll
        for (int i = 0; i < 2; ++i) {
            int idx = tid + i*256;                     // 0..511
            int row = idx >> 2;                        // 0..127
            int col0 = (idx & 3) * 8;                  // 0,8,16,24
            size_t gx = (size_t)(bm  + row)*K + k0 + col0;
            size_t gw = (size_t)(bn0 + row)*K + k0 + col0;
            int lo_ = ((row << 6) | (col0 << 1)) ^ ((row & 7) << 4);  // XOR swizzle (G4)
            *(ushort8_*)((char*)sXh + lo_) = *(const ushort8_*)(Xh + gx);
            *(ushort8_*)((char*)sXl + lo_) = *(const ushort8_*)(Xl + gx);
            *(ushort8_*)((char*)sWh + lo_) = *(const ushort8_*)(WTh + gw);
            *(ushort8_*)((char*)sWl + lo_) = *(const ushort8_*)(WTl + gw);
        }
        __syncthreads();

        int kb = (l >> 4) << 4;                        // byte offset of this lane's 8 k-elems
        bf16x8_ bh[4], bl4[4];
#pragma unroll
        for (int nf = 0; nf < 4; ++nf) {
            int rn = wc*64 + nf*16 + (l & 15);
            int o = ((rn << 6) | kb) ^ ((rn & 7) << 4);
            bh[nf]  = *(const bf16x8_*)((const char*)sWh + o);
            bl4[nf] = *(const bf16x8_*)((const char*)sWl + o);
        }
#pragma unroll
        for (int mf = 0; mf < 4; ++mf) {
            int rm = wr*64 + mf*16 + (l & 15);
            int o = ((rm << 6) | kb) ^ ((rm & 7) << 4);
            bf16x8_ ah = *(const bf16x8_*)((const char*)sXh + o);
            bf16x8_ al = *(const bf16x8_*)((const char*)sXl + o);
#pragma unroll
            for (int nf = 0; nf < 4; ++nf) {
                acc[mf][nf] = __builtin_amdgcn_mfma_f32_16x16x32_bf16(ah, bh[nf],  acc[mf][nf], 0, 0, 0);
                acc[mf][nf] = __builtin_amdgcn_mfma_f32_16x16x32_bf16(ah, bl4[nf], acc[mf][nf], 0, 0, 0);
                acc[mf][nf] = __builtin_amdgcn_mfma_f32_16x16x32_bf16(al, bh[nf],  acc[mf][nf], 0, 0, 0);
            }
        }
        __syncthreads();
    }

    // D layout (m89): row = (l>>4)*4 + reg, col = l&15
    int r0 = (l >> 4) << 2, cB = l & 15;
#pragma unroll
    for (int mf = 0; mf < 4; ++mf)
#pragma unroll
        for (int nf = 0; nf < 4; ++nf) {
            int col = bn0 + wc*64 + nf*16 + cB;
#pragma unroll
            for (int reg = 0; reg < 4; ++reg) {
                int row = bm + wr*64 + mf*16 + r0 + reg;
                PQ[(size_t)row*Ntot + col] = acc[mf][nf][reg];
            }
        }
}

// ---------------- edge combine: h = P[dst] + Q[src] + c ; lrelu; per-dst max; BN partials;
//                  per-block partial max (stride S between rows of P/Q) ----------------
__global__ void combine_kernel(const float* __restrict__ P, const float* __restrict__ Q,
                               const float* __restrict__ cvec, const int* __restrict__ src,
                               float* __restrict__ m_out, float* __restrict__ partial,
                               float* __restrict__ gpart, int C, int S) {
    int c = threadIdx.x;                 // blockDim.x == C
    int i0 = blockIdx.x * GRP;
    float cv = cvec[c];
    float sum = 0.f, ssq = 0.f;
    float bmx = -INFINITY;
    for (int g = 0; g < GRP; ++g) {
        int i = i0 + g;
        float p = P[(size_t)i*S + c] + cv;
        float mx = -INFINITY;
#pragma unroll
        for (int k = 0; k < K_; ++k) {
            int s = src[(size_t)i*K_ + k];
            float h = p + Q[(size_t)s*S + c];
            float l = (h >= 0.f) ? h : 0.2f*h;
            sum += l; ssq += l*l;
            mx = fmaxf(mx, l);
        }
        if (m_out) m_out[(size_t)i*C + c] = mx;
        bmx = fmaxf(bmx, mx);
    }
    gpart[(size_t)blockIdx.x*C + c] = bmx;
    partial[(size_t)blockIdx.x*2*C + c]     = sum;
    partial[(size_t)blockIdx.x*2*C + C + c] = ssq;
}

// ---------------- BN stats reduce -> scale/shift ----------------
__global__ __launch_bounds__(256) void reduce_kernel(const float* __restrict__ partial, int nblocks, int C,
                              const float* __restrict__ g, const float* __restrict__ be,
                              float* __restrict__ scale, float* __restrict__ shift) {
    int c = blockIdx.x;
    float s0 = 0.f, s1 = 0.f;
    for (int blk = threadIdx.x; blk < nblocks; blk += 256) {
        s0 += partial[(size_t)blk*2*C + c];
        s1 += partial[(size_t)blk*2*C + C + c];
    }
    __shared__ float l0[256], l1[256];
    l0[threadIdx.x] = s0; l1[threadIdx.x] = s1;
    __syncthreads();
    for (int off = 128; off > 0; off >>= 1) {
        if (threadIdx.x < off) {
            l0[threadIdx.x] += l0[threadIdx.x + off];
            l1[threadIdx.x] += l1[threadIdx.x + off];
        }
        __syncthreads();
    }
    if (threadIdx.x == 0) {
        float mean = l0[0] / (float)NEDGE_;
        float var  = l1[0] / (float)NEDGE_ - mean*mean;
        float sc = g[c] * rsqrtf(var + 1e-5f);
        scale[c] = sc;
        shift[c] = be[c] - mean*sc;
    }
}

// ---------------- fused global max-pool finalize ----------------
__global__ __launch_bounds__(1024) void gmax_finalize(
        const float* __restrict__ gp1, const float* __restrict__ gp2, const float* __restrict__ gp3,
        const float* __restrict__ sc1, const float* __restrict__ sh1,
        const float* __restrict__ sc2, const float* __restrict__ sh2,
        const float* __restrict__ sc3, const float* __restrict__ sh3,
        float* __restrict__ gfeat) {
    int b = blockIdx.x, grp = blockIdx.y;
    const float *gp, *sc, *sh; int C, c0, coff;
    if (grp == 0)      { gp = gp1; sc = sc1; sh = sh1; C = 64;  c0 = 0;            coff = 0;   }
    else if (grp <= 2) { gp = gp2; sc = sc2; sh = sh2; C = 128; c0 = (grp-1)*64;   coff = 64;  }
    else               { gp = gp3; sc = sc3; sh = sh3; C = 256; c0 = (grp-3)*64;   coff = 192; }
    int cl = threadIdx.x & 63;
    int stripe = threadIdx.x >> 6;   // 0..15
    int c = c0 + cl;
    float mx = -INFINITY;
    for (int ch = stripe; ch < CHUNKS_; ch += 16)
        mx = fmaxf(mx, gp[((size_t)b*CHUNKS_ + ch)*C + c]);
    __shared__ float red[16][64];
    red[stripe][cl] = mx;
    __syncthreads();
    for (int off = 8; off > 0; off >>= 1) {
        if (stripe < off) red[stripe][cl] = fmaxf(red[stripe][cl], red[stripe+off][cl]);
        __syncthreads();
    }
    if (stripe == 0)
        gfeat[b*448 + coff + c] = sc[c]*red[0][cl] + sh[c];
}

// ---------------- final head ----------------
__global__ __launch_bounds__(512) void final_kernel(const float* __restrict__ gfeat,
                             const float* __restrict__ Wf1, const float* __restrict__ bf1,
                             const float* __restrict__ gf, const float* __restrict__ bef,
                             const float* __restrict__ Wf2, const float* __restrict__ bf2,
                             float* __restrict__ out) {
    __shared__ float gf_s[B_][448];
    __shared__ float h_s[B_][512];
    int t = threadIdx.x;
    for (int e = t; e < B_*448; e += 512) gf_s[e/448][e%448] = gfeat[e];
    __syncthreads();
    float acc[B_];
#pragma unroll
    for (int r = 0; r < B_; ++r) acc[r] = bf1[t];
    for (int d = 0; d < 448; ++d) {
        float w = Wf1[(size_t)d*512 + t];
#pragma unroll
        for (int r = 0; r < B_; ++r) acc[r] += gf_s[r][d] * w;
    }
#pragma unroll
    for (int r = 0; r < B_; ++r) { float v = acc[r]; acc[r] = (v >= 0.f) ? v : 0.2f*v; }
    float mean = 0.f;
#pragma unroll
    for (int r = 0; r < B_; ++r) mean += acc[r];
    mean *= (1.0f/B_);
    float var = 0.f;
#pragma unroll
    for (int r = 0; r < B_; ++r) { float dd = acc[r] - mean; var += dd*dd; }
    var *= (1.0f/B_);
    float sc = gf[t] * rsqrtf(var + 1e-5f);
    float sh = bef[t] - mean*sc;
#pragma unroll
    for (int r = 0; r < B_; ++r) h_s[r][t] = acc[r]*sc + sh;
    __syncthreads();
    for (int e = t; e < B_*128; e += 512) {
        int r = e >> 7, c = e & 127;
        float a = bf2[c];
        for (int d = 0; d < 512; ++d) a += h_s[r][d] * Wf2[(size_t)d*128 + c];
        out[e] = a;
    }
}

// ---------------- host side ----------------
static void run_layer(const float* X, int Kin, int Kpad, int C,
                      const float* W, const float* b, const float* g, const float* be,
                      const float* scale_in, const float* shift_in,
                      float* PQ, unsigned short* Xh, unsigned short* Xl,
                      unsigned short* WTh, unsigned short* WTl, float* cvec,
                      const int* src, float* m_out, float* partial, float* gpart,
                      float* scale_out, float* shift_out, hipStream_t stream) {
    int total8 = BN_ * Kpad / 8;
    cast_split<<<(total8 + 255)/256, 256, 0, stream>>>(X, Xh, Xl, Kin, Kpad, total8);
    prep_WT<<<(2*C*Kpad + 255)/256, 256, 0, stream>>>(W, scale_in, WTh, WTl, Kin, C, Kpad);
    prep_c<<<(C + 63)/64, 64, 0, stream>>>(W, shift_in, b, cvec, Kin, C);
    mfma_dual<<<dim3(2*C/128, BN_/128), 256, 0, stream>>>(Xh, Xl, WTh, WTl, PQ, Kpad, 2*C);
    combine_kernel<<<BN_/GRP, C, 0, stream>>>(PQ, PQ + C, cvec, src, m_out, partial, gpart, C, 2*C);
    reduce_kernel<<<C, 256, 0, stream>>>(partial, BN_/GRP, C, g, be, scale_out, shift_out);
}

extern "C" void kernel_launch(void* const* d_in, const int* in_sizes, int n_in,
                              void* d_out, int out_size, void* d_ws, size_t ws_size,
                              hipStream_t stream) {
    (void)in_sizes; (void)n_in; (void)out_size; (void)ws_size;
    const float* points = (const float*)d_in[0];
    const float* W1 = (const float*)d_in[1];  const float* b1 = (const float*)d_in[2];
    const float* g1 = (const float*)d_in[3];  const float* be1 = (const float*)d_in[4];
    const float* W2 = (const float*)d_in[5];  const float* b2 = (const float*)d_in[6];
    const float* g2 = (const float*)d_in[7];  const float* be2 = (const float*)d_in[8];
    const float* W3 = (const float*)d_in[9];  const float* b3 = (const float*)d_in[10];
    const float* g3 = (const float*)d_in[11]; const float* be3 = (const float*)d_in[12];
    const float* Wf1 = (const float*)d_in[13]; const float* bf1 = (const float*)d_in[14];
    const float* gf = (const float*)d_in[15];  const float* bef = (const float*)d_in[16];
    const float* Wf2 = (const float*)d_in[17]; const float* bf2 = (const float*)d_in[18];
    float* out = (float*)d_out;

    size_t off = 0;
    char* base = (char*)d_ws;
    auto carve = [&](size_t bytes) -> void* {
        void* p = base + off;
        off += (bytes + 255) & ~(size_t)255;
        return p;
    };
    int*   src     = (int*)  carve((size_t)NEDGE_ * 4);
    float* PQ      = (float*)carve((size_t)BN_ * 512 * 4);   // 32MB; also kNN partial overlay
    float* m1      = (float*)carve((size_t)BN_ * 64 * 4);
    float* m2      = (float*)carve((size_t)BN_ * 128 * 4);
    float* gp1     = (float*)carve((size_t)(BN_/GRP) * 64 * 4);
    float* gp2     = (float*)carve((size_t)(BN_/GRP) * 128 * 4);
    float* gp3     = (float*)carve((size_t)(BN_/GRP) * 256 * 4);
    unsigned short* Xh  = (unsigned short*)carve((size_t)BN_ * 128 * 2);
    unsigned short* Xl  = (unsigned short*)carve((size_t)BN_ * 128 * 2);
    unsigned short* WTh = (unsigned short*)carve((size_t)512 * 128 * 2);
    unsigned short* WTl = (unsigned short*)carve((size_t)512 * 128 * 2);
    float* cvec    = (float*)carve(256 * 4);
    float* sc1     = (float*)carve(64 * 4);
    float* sh1     = (float*)carve(64 * 4);
    float* sc2     = (float*)carve(128 * 4);
    float* sh2     = (float*)carve(128 * 4);
    float* sc3     = (float*)carve(256 * 4);
    float* sh3     = (float*)carve(256 * 4);
    float* partial = (float*)carve((size_t)(BN_/GRP) * 2 * 256 * 4);
    float* gfeat   = (float*)carve((size_t)B_ * 448 * 4);

    // kNN: phase-1 partials (SEG_*BN_*K_*8B = 32MB) overlay PQ (dead until first mfma_dual)
    unsigned long long* part = (unsigned long long*)PQ;
    knn_part<<<dim3(BN_/256, SEG_), 256, 0, stream>>>(points, part);
    knn_merge<<<BN_/128, 128, 0, stream>>>(part, src);

    run_layer(points, IN_, 32, 64,  W1, b1, g1, be1, nullptr, nullptr,
              PQ, Xh, Xl, WTh, WTl, cvec, src, m1, partial, gp1, sc1, sh1, stream);
    run_layer(m1, 64, 64, 128, W2, b2, g2, be2, sc1, sh1,
              PQ, Xh, Xl, WTh, WTl, cvec, src, m2, partial, gp2, sc2, sh2, stream);
    run_layer(m2, 128, 128, 256, W3, b3, g3, be3, sc2, sh2,
              PQ, Xh, Xl, WTh, WTl, cvec, src, nullptr, partial, gp3, sc3, sh3, stream);

    gmax_finalize<<<dim3(B_, 7), 1024, 0, stream>>>(gp1, gp2, gp3,
                                                    sc1, sh1, sc2, sh2, sc3, sh3, gfeat);

    final_kernel<<<1, 512, 0, stream>>>(gfeat, Wf1, bf1, gf, bef, Wf2, bf2, out);
}

// Round 6
// 255.664 us; speedup vs baseline: 4.2673x; 1.1571x over previous
//
#include <hip/hip_runtime.h>
#include <math.h>

#define B_ 8
#define N_ 2048
#define K_ 8
#define IN_ 5
#define BN_ (B_*N_)
#define NEDGE_ (BN_*K_)
#define GRP 8
#define SEG_ 32
#define CSEG_ (N_/SEG_)   // 64 candidates per segment
#define CHUNKS_ (N_/GRP)  // 256 combine-blocks per batch

typedef unsigned short ushort8_ __attribute__((ext_vector_type(8)));
typedef short bf16x8_ __attribute__((ext_vector_type(8)));
typedef float f32x4_ __attribute__((ext_vector_type(4)));

// float -> bf16 (RNE), bf16 -> float
__device__ inline unsigned short f2bf(float f) {
    unsigned int u = __float_as_uint(f);
    u += 0x7fffu + ((u >> 16) & 1u);
    return (unsigned short)(u >> 16);
}
__device__ inline float bf2f(unsigned short h) {
    return __uint_as_float(((unsigned int)h) << 16);
}

// ordered-float: monotone map f32 -> u32
__device__ inline unsigned int ord_f32(float f) {
    unsigned int u = __float_as_uint(f);
    return (u & 0x80000000u) ? ~u : (u | 0x80000000u);
}

// ---------------- kNN phase 1: per-segment top-8 (u64 keys) ----------------
__global__ __launch_bounds__(256) void knn_part(const float* __restrict__ points,
                                                unsigned long long* __restrict__ part) {
    int tid = threadIdx.x;
    int q = blockIdx.x * 256 + tid;
    int b = q / N_;
    int n = q % N_;
    int seg = blockIdx.y;
    const float* pb = points + (size_t)b * N_ * IN_;

    __shared__ float4 sp4[CSEG_];
    if (tid < CSEG_) {
        int j = seg * CSEG_ + tid;
        float x = pb[(size_t)j*IN_+0], y = pb[(size_t)j*IN_+1], z = pb[(size_t)j*IN_+2];
        sp4[tid] = make_float4(x, y, z, x*x + y*y + z*z);
    }
    float qx = pb[(size_t)n*IN_+0], qy = pb[(size_t)n*IN_+1], qz = pb[(size_t)n*IN_+2];
    float qsq = qx*qx + qy*qy + qz*qz;
    __syncthreads();

    unsigned long long best[K_];
#pragma unroll
    for (int k = 0; k < K_; ++k) best[k] = ~0ull;

    auto ins = [&](unsigned long long cur) {
#pragma unroll
        for (int p = 0; p < K_; ++p) {
            unsigned long long lo = best[p] < cur ? best[p] : cur;
            unsigned long long hi = best[p] < cur ? cur : best[p];
            best[p] = lo; cur = hi;
        }
    };

    int jbase = seg * CSEG_;
    for (int jj = 0; jj < CSEG_; jj += 2) {
        float4 c0 = sp4[jj], c1 = sp4[jj+1];
        float d0 = qsq + c0.w - 2.0f*(qx*c0.x + qy*c0.y + qz*c0.z);
        float d1 = qsq + c1.w - 2.0f*(qx*c1.x + qy*c1.y + qz*c1.z);
        int j0 = jbase + jj, j1 = j0 + 1;
        unsigned long long k0 = ((unsigned long long)ord_f32(d0) << 32) | (unsigned int)j0;
        unsigned long long k1 = ((unsigned long long)ord_f32(d1) << 32) | (unsigned int)j1;
        if (j0 == n) k0 = ~0ull;            // branchless self-exclusion
        if (j1 == n) k1 = ~0ull;
        unsigned long long kmin = k0 < k1 ? k0 : k1;
        if (kmin < best[K_-1]) {            // ascending order: k0 then k1 (tie-break by idx)
            if (k0 < best[K_-1]) ins(k0);
            if (k1 < best[K_-1]) ins(k1);
        }
    }
    unsigned long long* op = part + ((size_t)seg * BN_ + q) * K_;
#pragma unroll
    for (int k = 0; k < K_; ++k) op[k] = best[k];
}

// ---------------- kNN phase 2: merge SEG_ sorted 8-lists ----------------
__global__ __launch_bounds__(128) void knn_merge(const unsigned long long* __restrict__ part,
                                                 int* __restrict__ src) {
    int q = blockIdx.x * 128 + threadIdx.x;
    int b = q / N_;
    unsigned long long best[K_];
#pragma unroll
    for (int k = 0; k < K_; ++k) best[k] = ~0ull;
    for (int s = 0; s < SEG_; ++s) {
        const unsigned long long* lp = part + ((size_t)s * BN_ + q) * K_;
#pragma unroll
        for (int k = 0; k < K_; ++k) {
            unsigned long long key = lp[k];
            if (key >= best[K_-1]) break;
            unsigned long long cur = key;
#pragma unroll
            for (int p = 0; p < K_; ++p) {
                unsigned long long lo = best[p] < cur ? best[p] : cur;
                unsigned long long hi = best[p] < cur ? cur : best[p];
                best[p] = lo; cur = hi;
            }
        }
    }
#pragma unroll
    for (int k = 0; k < K_; ++k)
        src[(size_t)q*K_ + k] = b*N_ + (int)(best[k] & 0xFFFFFFFFu);
}

// ---------------- input cast (layer 1 only): fp32 [M][Kin] -> split bf16 [M][Kpad] ----------------
__global__ __launch_bounds__(256) void cast_split(const float* __restrict__ X,
                                                  unsigned short* __restrict__ Xh,
                                                  unsigned short* __restrict__ Xl,
                                                  int Kin, int Kpad, int total8) {
    int t = blockIdx.x * 256 + threadIdx.x;
    if (t >= total8) return;
    int vpr = Kpad >> 3;
    int m = t / vpr;
    int k0 = (t % vpr) * 8;
    ushort8_ vh, vl;
#pragma unroll
    for (int j = 0; j < 8; ++j) {
        int k = k0 + j;
        float v = (k < Kin) ? X[(size_t)m*Kin + k] : 0.0f;
        unsigned short h = f2bf(v);
        vh[j] = h;
        vl[j] = f2bf(v - bf2f(h));
    }
    *(ushort8_*)(Xh + (size_t)m*Kpad + k0) = vh;
    *(ushort8_*)(Xl + (size_t)m*Kpad + k0) = vl;
}

// ---------------- fused weight prep: WT split-bf16 (BN fold) + c' vector ----------------
__global__ __launch_bounds__(256) void prep_layer(const float* __restrict__ W,
                                                  const float* __restrict__ scale,
                                                  const float* __restrict__ shift,
                                                  const float* __restrict__ bias,
                                                  unsigned short* __restrict__ WTh,
                                                  unsigned short* __restrict__ WTl,
                                                  float* __restrict__ cvec,
                                                  int Cin, int C, int Kpad) {
    int idx = blockIdx.x * 256 + threadIdx.x;
    int nWT = 2*C*Kpad;
    if (idx < nWT) {
        int n = idx / Kpad;
        int k = idx % Kpad;
        float val = 0.0f;
        if (k < Cin) {
            float s = scale ? scale[k] : 1.0f;
            if (n < C) val = s * (W[(size_t)k*C + n] - W[(size_t)(Cin+k)*C + n]);
            else       val = s * W[(size_t)(Cin+k)*C + (n - C)];
        }
        unsigned short h = f2bf(val);
        WTh[(size_t)n*Kpad + k] = h;
        WTl[(size_t)n*Kpad + k] = f2bf(val - bf2f(h));
    } else if (idx < nWT + C) {
        int c = idx - nWT;
        float acc = bias[c];
        if (shift)
            for (int d = 0; d < Cin; ++d) acc += shift[d] * W[(size_t)d*C + c];
        cvec[c] = acc;
    }
}

// ---------------- split-bf16 MFMA GEMM: PQ[M][Ntot] = X[M][K] @ WT^T, 128x128 tile, BK=32 ----------------
__global__ __launch_bounds__(256) void mfma_dual(const unsigned short* __restrict__ Xh,
                                                 const unsigned short* __restrict__ Xl,
                                                 const unsigned short* __restrict__ WTh,
                                                 const unsigned short* __restrict__ WTl,
                                                 float* __restrict__ PQ, int K, int Ntot) {
    __shared__ unsigned short sXh[128*32], sXl[128*32], sWh[128*32], sWl[128*32];
    int tid = threadIdx.x, l = tid & 63, w = tid >> 6;
    int wr = w >> 1, wc = w & 1;                       // 2x2 waves -> 64x64 per wave
    int bm = blockIdx.y * 128, bn0 = blockIdx.x * 128;

    f32x4_ acc[4][4];
#pragma unroll
    for (int i = 0; i < 4; ++i)
#pragma unroll
        for (int j = 0; j < 4; ++j) acc[i][j] = (f32x4_){0.f, 0.f, 0.f, 0.f};

    for (int k0 = 0; k0 < K; k0 += 32) {
#pragma unroll
        for (int i = 0; i < 2; ++i) {
            int idx = tid + i*256;                     // 0..511
            int row = idx >> 2;                        // 0..127
            int col0 = (idx & 3) * 8;                  // 0,8,16,24
            size_t gx = (size_t)(bm  + row)*K + k0 + col0;
            size_t gw = (size_t)(bn0 + row)*K + k0 + col0;
            int lo_ = ((row << 6) | (col0 << 1)) ^ ((row & 7) << 4);  // XOR swizzle
            *(ushort8_*)((char*)sXh + lo_) = *(const ushort8_*)(Xh + gx);
            *(ushort8_*)((char*)sXl + lo_) = *(const ushort8_*)(Xl + gx);
            *(ushort8_*)((char*)sWh + lo_) = *(const ushort8_*)(WTh + gw);
            *(ushort8_*)((char*)sWl + lo_) = *(const ushort8_*)(WTl + gw);
        }
        __syncthreads();

        int kb = (l >> 4) << 4;                        // byte offset of this lane's 8 k-elems
        bf16x8_ bh[4], bl4[4];
#pragma unroll
        for (int nf = 0; nf < 4; ++nf) {
            int rn = wc*64 + nf*16 + (l & 15);
            int o = ((rn << 6) | kb) ^ ((rn & 7) << 4);
            bh[nf]  = *(const bf16x8_*)((const char*)sWh + o);
            bl4[nf] = *(const bf16x8_*)((const char*)sWl + o);
        }
#pragma unroll
        for (int mf = 0; mf < 4; ++mf) {
            int rm = wr*64 + mf*16 + (l & 15);
            int o = ((rm << 6) | kb) ^ ((rm & 7) << 4);
            bf16x8_ ah = *(const bf16x8_*)((const char*)sXh + o);
            bf16x8_ al = *(const bf16x8_*)((const char*)sXl + o);
#pragma unroll
            for (int nf = 0; nf < 4; ++nf) {
                acc[mf][nf] = __builtin_amdgcn_mfma_f32_16x16x32_bf16(ah, bh[nf],  acc[mf][nf], 0, 0, 0);
                acc[mf][nf] = __builtin_amdgcn_mfma_f32_16x16x32_bf16(ah, bl4[nf], acc[mf][nf], 0, 0, 0);
                acc[mf][nf] = __builtin_amdgcn_mfma_f32_16x16x32_bf16(al, bh[nf],  acc[mf][nf], 0, 0, 0);
            }
        }
        __syncthreads();
    }

    int r0 = (l >> 4) << 2, cB = l & 15;
#pragma unroll
    for (int mf = 0; mf < 4; ++mf)
#pragma unroll
        for (int nf = 0; nf < 4; ++nf) {
            int col = bn0 + wc*64 + nf*16 + cB;
#pragma unroll
            for (int reg = 0; reg < 4; ++reg) {
                int row = bm + wr*64 + mf*16 + r0 + reg;
                PQ[(size_t)row*Ntot + col] = acc[mf][nf][reg];
            }
        }
}

// ---------------- edge combine: h = P[dst] + Q[src] + c ; lrelu; per-dst max -> split-bf16 X_next;
//                  BN partials; per-block partial max ----------------
__global__ void combine_kernel(const float* __restrict__ P, const float* __restrict__ Q,
                               const float* __restrict__ cvec, const int* __restrict__ src,
                               unsigned short* __restrict__ Xh_out, unsigned short* __restrict__ Xl_out,
                               float* __restrict__ partial, float* __restrict__ gpart,
                               int C, int S) {
    int c = threadIdx.x;                 // blockDim.x == C
    int i0 = blockIdx.x * GRP;
    float cv = cvec[c];
    float sum = 0.f, ssq = 0.f;
    float bmx = -INFINITY;
    for (int g = 0; g < GRP; ++g) {
        int i = i0 + g;
        float p = P[(size_t)i*S + c] + cv;
        float mx = -INFINITY;
#pragma unroll
        for (int k = 0; k < K_; ++k) {
            int s = src[(size_t)i*K_ + k];
            float h = p + Q[(size_t)s*S + c];
            float l = (h >= 0.f) ? h : 0.2f*h;
            sum += l; ssq += l*l;
            mx = fmaxf(mx, l);
        }
        if (Xh_out) {                    // next layer's input, split-bf16 (Kpad_next == C)
            unsigned short hh = f2bf(mx);
            Xh_out[(size_t)i*C + c] = hh;
            Xl_out[(size_t)i*C + c] = f2bf(mx - bf2f(hh));
        }
        bmx = fmaxf(bmx, mx);
    }
    gpart[(size_t)blockIdx.x*C + c] = bmx;
    partial[(size_t)blockIdx.x*2*C + c]     = sum;
    partial[(size_t)blockIdx.x*2*C + C + c] = ssq;
}

// ---------------- BN stats reduce -> scale/shift ----------------
__global__ __launch_bounds__(256) void reduce_kernel(const float* __restrict__ partial, int nblocks, int C,
                              const float* __restrict__ g, const float* __restrict__ be,
                              float* __restrict__ scale, float* __restrict__ shift) {
    int c = blockIdx.x;
    float s0 = 0.f, s1 = 0.f;
    for (int blk = threadIdx.x; blk < nblocks; blk += 256) {
        s0 += partial[(size_t)blk*2*C + c];
        s1 += partial[(size_t)blk*2*C + C + c];
    }
    __shared__ float l0[256], l1[256];
    l0[threadIdx.x] = s0; l1[threadIdx.x] = s1;
    __syncthreads();
    for (int off = 128; off > 0; off >>= 1) {
        if (threadIdx.x < off) {
            l0[threadIdx.x] += l0[threadIdx.x + off];
            l1[threadIdx.x] += l1[threadIdx.x + off];
        }
        __syncthreads();
    }
    if (threadIdx.x == 0) {
        float mean = l0[0] / (float)NEDGE_;
        float var  = l1[0] / (float)NEDGE_ - mean*mean;
        float sc = g[c] * rsqrtf(var + 1e-5f);
        scale[c] = sc;
        shift[c] = be[c] - mean*sc;
    }
}

// ---------------- fused global max-pool finalize ----------------
__global__ __launch_bounds__(1024) void gmax_finalize(
        const float* __restrict__ gp1, const float* __restrict__ gp2, const float* __restrict__ gp3,
        const float* __restrict__ sc1, const float* __restrict__ sh1,
        const float* __restrict__ sc2, const float* __restrict__ sh2,
        const float* __restrict__ sc3, const float* __restrict__ sh3,
        float* __restrict__ gfeat) {
    int b = blockIdx.x, grp = blockIdx.y;
    const float *gp, *sc, *sh; int C, c0, coff;
    if (grp == 0)      { gp = gp1; sc = sc1; sh = sh1; C = 64;  c0 = 0;            coff = 0;   }
    else if (grp <= 2) { gp = gp2; sc = sc2; sh = sh2; C = 128; c0 = (grp-1)*64;   coff = 64;  }
    else               { gp = gp3; sc = sc3; sh = sh3; C = 256; c0 = (grp-3)*64;   coff = 192; }
    int cl = threadIdx.x & 63;
    int stripe = threadIdx.x >> 6;   // 0..15
    int c = c0 + cl;
    float mx = -INFINITY;
    for (int ch = stripe; ch < CHUNKS_; ch += 16)
        mx = fmaxf(mx, gp[((size_t)b*CHUNKS_ + ch)*C + c]);
    __shared__ float red[16][64];
    red[stripe][cl] = mx;
    __syncthreads();
    for (int off = 8; off > 0; off >>= 1) {
        if (stripe < off) red[stripe][cl] = fmaxf(red[stripe][cl], red[stripe+off][cl]);
        __syncthreads();
    }
    if (stripe == 0)
        gfeat[b*448 + coff + c] = sc[c]*red[0][cl] + sh[c];
}

// ---------------- head part 1: H = BN(lrelu(gfeat@Wf1 + bf1)) ; BN is per-column over 8 rows ----------------
// grid 8 blocks x 256 threads: block covers 64 columns, 4 d-stripes of 112
__global__ __launch_bounds__(256) void final1(const float* __restrict__ gfeat,
                                              const float* __restrict__ Wf1, const float* __restrict__ bf1,
                                              const float* __restrict__ gf, const float* __restrict__ bef,
                                              float* __restrict__ H) {
    __shared__ float gfs[B_][448];
    __shared__ float red[4][64][B_];
    int t = threadIdx.x;
    int cl = t & 63;
    int stripe = t >> 6;                 // 0..3
    int c = blockIdx.x * 64 + cl;
    for (int e = t; e < B_*448; e += 256) gfs[e/448][e%448] = gfeat[e];
    __syncthreads();
    float acc[B_] = {};
    for (int d = stripe*112; d < stripe*112 + 112; ++d) {
        float w = Wf1[(size_t)d*512 + c];
#pragma unroll
        for (int r = 0; r < B_; ++r) acc[r] += gfs[r][d] * w;
    }
#pragma unroll
    for (int r = 0; r < B_; ++r) red[stripe][cl][r] = acc[r];
    __syncthreads();
    if (stripe == 0) {
        float v[B_];
        float b1v = bf1[c];
#pragma unroll
        for (int r = 0; r < B_; ++r) {
            float a = red[0][cl][r] + red[1][cl][r] + red[2][cl][r] + red[3][cl][r] + b1v;
            v[r] = (a >= 0.f) ? a : 0.2f*a;
        }
        float mean = 0.f;
#pragma unroll
        for (int r = 0; r < B_; ++r) mean += v[r];
        mean *= (1.0f/B_);
        float var = 0.f;
#pragma unroll
        for (int r = 0; r < B_; ++r) { float dd = v[r] - mean; var += dd*dd; }
        var *= (1.0f/B_);
        float sc = gf[c] * rsqrtf(var + 1e-5f);
        float sh = bef[c] - mean*sc;
#pragma unroll
        for (int r = 0; r < B_; ++r) H[(size_t)r*512 + c] = v[r]*sc + sh;
    }
}

// ---------------- head part 2: out = H @ Wf2 + bf2 ----------------
// grid 8 blocks x 128 threads: block = one batch row
__global__ __launch_bounds__(128) void final2(const float* __restrict__ H,
                                              const float* __restrict__ Wf2, const float* __restrict__ bf2,
                                              float* __restrict__ out) {
    int b = blockIdx.x, c = threadIdx.x;
    __shared__ float hs[512];
    for (int e = c; e < 512; e += 128) hs[e] = H[(size_t)b*512 + e];
    __syncthreads();
    float a = bf2[c];
    for (int d = 0; d < 512; ++d) a += hs[d] * Wf2[(size_t)d*128 + c];
    out[b*128 + c] = a;
}

// ---------------- host side ----------------
static void run_layer(int Kpad, int C,
                      const float* W, const float* g, const float* be, const float* b,
                      const float* scale_in, const float* shift_in,
                      float* PQ, const unsigned short* Xh_in, const unsigned short* Xl_in,
                      unsigned short* Xh_next, unsigned short* Xl_next,
                      unsigned short* WTh, unsigned short* WTl, float* cvec,
                      const int* src, float* partial, float* gpart,
                      float* scale_out, float* shift_out, hipStream_t stream) {
    int Cin = (scale_in == nullptr) ? IN_ : Kpad;   // layer1: Cin=5, else Cin==Kpad
    int nPrep = 2*C*Kpad + C;
    prep_layer<<<(nPrep + 255)/256, 256, 0, stream>>>(W, scale_in, shift_in, b, WTh, WTl, cvec, Cin, C, Kpad);
    mfma_dual<<<dim3(2*C/128, BN_/128), 256, 0, stream>>>(Xh_in, Xl_in, WTh, WTl, PQ, Kpad, 2*C);
    combine_kernel<<<BN_/GRP, C, 0, stream>>>(PQ, PQ + C, cvec, src, Xh_next, Xl_next, partial, gpart, C, 2*C);
    reduce_kernel<<<C, 256, 0, stream>>>(partial, BN_/GRP, C, g, be, scale_out, shift_out);
}

extern "C" void kernel_launch(void* const* d_in, const int* in_sizes, int n_in,
                              void* d_out, int out_size, void* d_ws, size_t ws_size,
                              hipStream_t stream) {
    (void)in_sizes; (void)n_in; (void)out_size; (void)ws_size;
    const float* points = (const float*)d_in[0];
    const float* W1 = (const float*)d_in[1];  const float* b1 = (const float*)d_in[2];
    const float* g1 = (const float*)d_in[3];  const float* be1 = (const float*)d_in[4];
    const float* W2 = (const float*)d_in[5];  const float* b2 = (const float*)d_in[6];
    const float* g2 = (const float*)d_in[7];  const float* be2 = (const float*)d_in[8];
    const float* W3 = (const float*)d_in[9];  const float* b3 = (const float*)d_in[10];
    const float* g3 = (const float*)d_in[11]; const float* be3 = (const float*)d_in[12];
    const float* Wf1 = (const float*)d_in[13]; const float* bf1 = (const float*)d_in[14];
    const float* gf = (const float*)d_in[15];  const float* bef = (const float*)d_in[16];
    const float* Wf2 = (const float*)d_in[17]; const float* bf2 = (const float*)d_in[18];
    float* out = (float*)d_out;

    size_t off = 0;
    char* base = (char*)d_ws;
    auto carve = [&](size_t bytes) -> void* {
        void* p = base + off;
        off += (bytes + 255) & ~(size_t)255;
        return p;
    };
    int*   src     = (int*)  carve((size_t)NEDGE_ * 4);
    float* PQ      = (float*)carve((size_t)BN_ * 512 * 4);   // 32MB; also kNN partial overlay
    float* gp1     = (float*)carve((size_t)(BN_/GRP) * 64 * 4);
    float* gp2     = (float*)carve((size_t)(BN_/GRP) * 128 * 4);
    float* gp3     = (float*)carve((size_t)(BN_/GRP) * 256 * 4);
    unsigned short* XhA = (unsigned short*)carve((size_t)BN_ * 128 * 2);
    unsigned short* XlA = (unsigned short*)carve((size_t)BN_ * 128 * 2);
    unsigned short* XhB = (unsigned short*)carve((size_t)BN_ * 128 * 2);
    unsigned short* XlB = (unsigned short*)carve((size_t)BN_ * 128 * 2);
    unsigned short* WTh = (unsigned short*)carve((size_t)512 * 128 * 2);
    unsigned short* WTl = (unsigned short*)carve((size_t)512 * 128 * 2);
    float* cvec    = (float*)carve(256 * 4);
    float* sc1     = (float*)carve(64 * 4);
    float* sh1     = (float*)carve(64 * 4);
    float* sc2     = (float*)carve(128 * 4);
    float* sh2     = (float*)carve(128 * 4);
    float* sc3     = (float*)carve(256 * 4);
    float* sh3     = (float*)carve(256 * 4);
    float* partial = (float*)carve((size_t)(BN_/GRP) * 2 * 256 * 4);
    float* gfeat   = (float*)carve((size_t)B_ * 448 * 4);
    float* H       = (float*)carve((size_t)B_ * 512 * 4);

    // kNN: phase-1 partials (SEG_*BN_*K_*8B = 32MB) overlay PQ (dead until first mfma_dual)
    unsigned long long* part = (unsigned long long*)PQ;
    knn_part<<<dim3(BN_/256, SEG_), 256, 0, stream>>>(points, part);
    knn_merge<<<BN_/128, 128, 0, stream>>>(part, src);

    // layer 1 input: points -> split bf16, Kpad=32
    int total8 = BN_ * 32 / 8;
    cast_split<<<(total8 + 255)/256, 256, 0, stream>>>(points, XhA, XlA, IN_, 32, total8);

    run_layer(32, 64,  W1, g1, be1, b1, nullptr, nullptr,
              PQ, XhA, XlA, XhB, XlB, WTh, WTl, cvec, src, partial, gp1, sc1, sh1, stream);
    run_layer(64, 128, W2, g2, be2, b2, sc1, sh1,
              PQ, XhB, XlB, XhA, XlA, WTh, WTl, cvec, src, partial, gp2, sc2, sh2, stream);
    run_layer(128, 256, W3, g3, be3, b3, sc2, sh2,
              PQ, XhA, XlA, nullptr, nullptr, WTh, WTl, cvec, src, partial, gp3, sc3, sh3, stream);

    gmax_finalize<<<dim3(B_, 7), 1024, 0, stream>>>(gp1, gp2, gp3,
                                                    sc1, sh1, sc2, sh2, sc3, sh3, gfeat);

    final1<<<8, 256, 0, stream>>>(gfeat, Wf1, bf1, gf, bef, H);
    final2<<<8, 128, 0, stream>>>(H, Wf2, bf2, out);
}

// Round 7
// 250.970 us; speedup vs baseline: 4.3471x; 1.0187x over previous
//
#include <hip/hip_runtime.h>
#include <math.h>

#define B_ 8
#define N_ 2048
#define K_ 8
#define IN_ 5
#define BN_ (B_*N_)
#define NEDGE_ (BN_*K_)
#define GRP 8
#define SEG_ 32
#define CSEG_ (N_/SEG_)   // 64 candidates per segment
#define CHUNKS_ (N_/GRP)  // 256 combine-blocks per batch

typedef unsigned short ushort8_ __attribute__((ext_vector_type(8)));
typedef short bf16x8_ __attribute__((ext_vector_type(8)));
typedef float f32x4_ __attribute__((ext_vector_type(4)));

// float -> bf16 (RNE), bf16 -> float
__device__ inline unsigned short f2bf(float f) {
    unsigned int u = __float_as_uint(f);
    u += 0x7fffu + ((u >> 16) & 1u);
    return (unsigned short)(u >> 16);
}
__device__ inline float bf2f(unsigned short h) {
    return __uint_as_float(((unsigned int)h) << 16);
}

// ordered-float: monotone map f32 -> u32
__device__ inline unsigned int ord_f32(float f) {
    unsigned int u = __float_as_uint(f);
    return (u & 0x80000000u) ? ~u : (u | 0x80000000u);
}

// ---------------- kNN phase 1: per-segment top-8; candidates via block-uniform (scalar) loads ----------------
__global__ __launch_bounds__(256) void knn_part(const float4* __restrict__ P4,
                                                unsigned long long* __restrict__ part) {
    int tid = threadIdx.x;
    int q = blockIdx.x * 256 + tid;     // block stays within one batch (2048 % 256 == 0)
    int b = q >> 11;                    // q / N_
    int nloc = q & (N_-1);              // local idx within batch
    int seg = blockIdx.y;

    float4 qp = P4[q];
    float qx2 = -2.0f*qp.x, qy2 = -2.0f*qp.y, qz2 = -2.0f*qp.z;
    float qsq = qp.w;

    unsigned long long best[K_];
#pragma unroll
    for (int k = 0; k < K_; ++k) best[k] = ~0ull;

    const float4* __restrict__ cb = P4 + (size_t)b*N_ + (size_t)seg*CSEG_;  // uniform base
    int jbase = seg * CSEG_;

#pragma unroll 8
    for (int jj = 0; jj < CSEG_; ++jj) {
        float4 c = cb[jj];              // uniform address -> scalar load (SGPR operands)
        float d = qsq + c.w;
        d = fmaf(qx2, c.x, d);
        d = fmaf(qy2, c.y, d);
        d = fmaf(qz2, c.z, d);
        int jg = jbase + jj;
        d = (jg == nloc) ? INFINITY : d;   // self-exclusion (INF keys always expelled: 63 finite cands)
        unsigned long long key = ((unsigned long long)ord_f32(d) << 32) | (unsigned int)jg;
        if (key < best[K_-1]) {
            unsigned long long cur = key;
#pragma unroll
            for (int p = 0; p < K_; ++p) {
                unsigned long long lo = best[p] < cur ? best[p] : cur;
                unsigned long long hi = best[p] < cur ? cur : best[p];
                best[p] = lo; cur = hi;
            }
        }
    }
    unsigned long long* op = part + ((size_t)seg * BN_ + q) * K_;
#pragma unroll
    for (int k = 0; k < K_; ++k) op[k] = best[k];
}

// ---------------- kNN phase 2: merge SEG_ sorted 8-lists ----------------
__global__ __launch_bounds__(128) void knn_merge(const unsigned long long* __restrict__ part,
                                                 int* __restrict__ src) {
    int q = blockIdx.x * 128 + threadIdx.x;
    int b = q / N_;
    unsigned long long best[K_];
#pragma unroll
    for (int k = 0; k < K_; ++k) best[k] = ~0ull;
    for (int s = 0; s < SEG_; ++s) {
        const unsigned long long* lp = part + ((size_t)s * BN_ + q) * K_;
#pragma unroll
        for (int k = 0; k < K_; ++k) {
            unsigned long long key = lp[k];
            if (key >= best[K_-1]) break;
            unsigned long long cur = key;
#pragma unroll
            for (int p = 0; p < K_; ++p) {
                unsigned long long lo = best[p] < cur ? best[p] : cur;
                unsigned long long hi = best[p] < cur ? cur : best[p];
                best[p] = lo; cur = hi;
            }
        }
    }
#pragma unroll
    for (int k = 0; k < K_; ++k)
        src[(size_t)q*K_ + k] = b*N_ + (int)(best[k] & 0xFFFFFFFFu);
}

// ---------------- layer-1 input cast + packed P4 build (runs FIRST) ----------------
__global__ __launch_bounds__(256) void cast_split(const float* __restrict__ X,
                                                  unsigned short* __restrict__ Xh,
                                                  unsigned short* __restrict__ Xl,
                                                  float4* __restrict__ P4,
                                                  int Kin, int Kpad, int total8) {
    int t = blockIdx.x * 256 + threadIdx.x;
    if (t < total8) {
        int vpr = Kpad >> 3;
        int m = t / vpr;
        int k0 = (t % vpr) * 8;
        ushort8_ vh, vl;
#pragma unroll
        for (int j = 0; j < 8; ++j) {
            int k = k0 + j;
            float v = (k < Kin) ? X[(size_t)m*Kin + k] : 0.0f;
            unsigned short h = f2bf(v);
            vh[j] = h;
            vl[j] = f2bf(v - bf2f(h));
        }
        *(ushort8_*)(Xh + (size_t)m*Kpad + k0) = vh;
        *(ushort8_*)(Xl + (size_t)m*Kpad + k0) = vl;
    }
    if (t < BN_) {
        const float* p = X + (size_t)t*Kin;
        float x = p[0], y = p[1], z = p[2];
        P4[t] = make_float4(x, y, z, x*x + y*y + z*z);
    }
}

// ---------------- fused weight prep: WT split-bf16 (BN fold) + c' vector ----------------
__global__ __launch_bounds__(256) void prep_layer(const float* __restrict__ W,
                                                  const float* __restrict__ scale,
                                                  const float* __restrict__ shift,
                                                  const float* __restrict__ bias,
                                                  unsigned short* __restrict__ WTh,
                                                  unsigned short* __restrict__ WTl,
                                                  float* __restrict__ cvec,
                                                  int Cin, int C, int Kpad) {
    int idx = blockIdx.x * 256 + threadIdx.x;
    int nWT = 2*C*Kpad;
    if (idx < nWT) {
        int n = idx / Kpad;
        int k = idx % Kpad;
        float val = 0.0f;
        if (k < Cin) {
            float s = scale ? scale[k] : 1.0f;
            if (n < C) val = s * (W[(size_t)k*C + n] - W[(size_t)(Cin+k)*C + n]);
            else       val = s * W[(size_t)(Cin+k)*C + (n - C)];
        }
        unsigned short h = f2bf(val);
        WTh[(size_t)n*Kpad + k] = h;
        WTl[(size_t)n*Kpad + k] = f2bf(val - bf2f(h));
    } else if (idx < nWT + C) {
        int c = idx - nWT;
        float acc = bias[c];
        if (shift)
            for (int d = 0; d < Cin; ++d) acc += shift[d] * W[(size_t)d*C + c];
        cvec[c] = acc;
    }
}

// ---------------- split-bf16 MFMA GEMM: PQ[M][Ntot] = X[M][K] @ WT^T, 128x128 tile, BK=32 ----------------
__global__ __launch_bounds__(256) void mfma_dual(const unsigned short* __restrict__ Xh,
                                                 const unsigned short* __restrict__ Xl,
                                                 const unsigned short* __restrict__ WTh,
                                                 const unsigned short* __restrict__ WTl,
                                                 float* __restrict__ PQ, int K, int Ntot) {
    __shared__ unsigned short sXh[128*32], sXl[128*32], sWh[128*32], sWl[128*32];
    int tid = threadIdx.x, l = tid & 63, w = tid >> 6;
    int wr = w >> 1, wc = w & 1;                       // 2x2 waves -> 64x64 per wave
    int bm = blockIdx.y * 128, bn0 = blockIdx.x * 128;

    f32x4_ acc[4][4];
#pragma unroll
    for (int i = 0; i < 4; ++i)
#pragma unroll
        for (int j = 0; j < 4; ++j) acc[i][j] = (f32x4_){0.f, 0.f, 0.f, 0.f};

    for (int k0 = 0; k0 < K; k0 += 32) {
#pragma unroll
        for (int i = 0; i < 2; ++i) {
            int idx = tid + i*256;                     // 0..511
            int row = idx >> 2;                        // 0..127
            int col0 = (idx & 3) * 8;                  // 0,8,16,24
            size_t gx = (size_t)(bm  + row)*K + k0 + col0;
            size_t gw = (size_t)(bn0 + row)*K + k0 + col0;
            int lo_ = ((row << 6) | (col0 << 1)) ^ ((row & 7) << 4);  // XOR swizzle
            *(ushort8_*)((char*)sXh + lo_) = *(const ushort8_*)(Xh + gx);
            *(ushort8_*)((char*)sXl + lo_) = *(const ushort8_*)(Xl + gx);
            *(ushort8_*)((char*)sWh + lo_) = *(const ushort8_*)(WTh + gw);
            *(ushort8_*)((char*)sWl + lo_) = *(const ushort8_*)(WTl + gw);
        }
        __syncthreads();

        int kb = (l >> 4) << 4;                        // byte offset of this lane's 8 k-elems
        bf16x8_ bh[4], bl4[4];
#pragma unroll
        for (int nf = 0; nf < 4; ++nf) {
            int rn = wc*64 + nf*16 + (l & 15);
            int o = ((rn << 6) | kb) ^ ((rn & 7) << 4);
            bh[nf]  = *(const bf16x8_*)((const char*)sWh + o);
            bl4[nf] = *(const bf16x8_*)((const char*)sWl + o);
        }
#pragma unroll
        for (int mf = 0; mf < 4; ++mf) {
            int rm = wr*64 + mf*16 + (l & 15);
            int o = ((rm << 6) | kb) ^ ((rm & 7) << 4);
            bf16x8_ ah = *(const bf16x8_*)((const char*)sXh + o);
            bf16x8_ al = *(const bf16x8_*)((const char*)sXl + o);
#pragma unroll
            for (int nf = 0; nf < 4; ++nf) {
                acc[mf][nf] = __builtin_amdgcn_mfma_f32_16x16x32_bf16(ah, bh[nf],  acc[mf][nf], 0, 0, 0);
                acc[mf][nf] = __builtin_amdgcn_mfma_f32_16x16x32_bf16(ah, bl4[nf], acc[mf][nf], 0, 0, 0);
                acc[mf][nf] = __builtin_amdgcn_mfma_f32_16x16x32_bf16(al, bh[nf],  acc[mf][nf], 0, 0, 0);
            }
        }
        __syncthreads();
    }

    int r0 = (l >> 4) << 2, cB = l & 15;
#pragma unroll
    for (int mf = 0; mf < 4; ++mf)
#pragma unroll
        for (int nf = 0; nf < 4; ++nf) {
            int col = bn0 + wc*64 + nf*16 + cB;
#pragma unroll
            for (int reg = 0; reg < 4; ++reg) {
                int row = bm + wr*64 + mf*16 + r0 + reg;
                PQ[(size_t)row*Ntot + col] = acc[mf][nf][reg];
            }
        }
}

// ---------------- edge combine: h = P[dst] + Q[src] + c ; lrelu; per-dst max -> split-bf16 X_next;
//                  BN partials; per-block partial max. XCD-swizzled: batch b -> XCD b ----------------
__global__ void combine_kernel(const float* __restrict__ P, const float* __restrict__ Q,
                               const float* __restrict__ cvec, const int* __restrict__ src,
                               unsigned short* __restrict__ Xh_out, unsigned short* __restrict__ Xl_out,
                               float* __restrict__ partial, float* __restrict__ gpart,
                               int C, int S) {
    int pb = blockIdx.x;
    int lb = (pb & 7) * CHUNKS_ + (pb >> 3);   // bijective: XCD (pb%8) gets all blocks of batch pb%8
    int c = threadIdx.x;                 // blockDim.x == C
    int i0 = lb * GRP;
    float cv = cvec[c];
    float sum = 0.f, ssq = 0.f;
    float bmx = -INFINITY;
    for (int g = 0; g < GRP; ++g) {
        int i = i0 + g;
        float p = P[(size_t)i*S + c] + cv;
        float mx = -INFINITY;
#pragma unroll
        for (int k = 0; k < K_; ++k) {
            int s = src[(size_t)i*K_ + k];
            float h = p + Q[(size_t)s*S + c];
            float l = (h >= 0.f) ? h : 0.2f*h;
            sum += l; ssq += l*l;
            mx = fmaxf(mx, l);
        }
        if (Xh_out) {                    // next layer's input, split-bf16 (Kpad_next == C)
            unsigned short hh = f2bf(mx);
            Xh_out[(size_t)i*C + c] = hh;
            Xl_out[(size_t)i*C + c] = f2bf(mx - bf2f(hh));
        }
        bmx = fmaxf(bmx, mx);
    }
    gpart[(size_t)lb*C + c] = bmx;
    partial[(size_t)lb*2*C + c]     = sum;
    partial[(size_t)lb*2*C + C + c] = ssq;
}

// ---------------- BN stats reduce -> scale/shift ----------------
__global__ __launch_bounds__(256) void reduce_kernel(const float* __restrict__ partial, int nblocks, int C,
                              const float* __restrict__ g, const float* __restrict__ be,
                              float* __restrict__ scale, float* __restrict__ shift) {
    int c = blockIdx.x;
    float s0 = 0.f, s1 = 0.f;
    for (int blk = threadIdx.x; blk < nblocks; blk += 256) {
        s0 += partial[(size_t)blk*2*C + c];
        s1 += partial[(size_t)blk*2*C + C + c];
    }
    __shared__ float l0[256], l1[256];
    l0[threadIdx.x] = s0; l1[threadIdx.x] = s1;
    __syncthreads();
    for (int off = 128; off > 0; off >>= 1) {
        if (threadIdx.x < off) {
            l0[threadIdx.x] += l0[threadIdx.x + off];
            l1[threadIdx.x] += l1[threadIdx.x + off];
        }
        __syncthreads();
    }
    if (threadIdx.x == 0) {
        float mean = l0[0] / (float)NEDGE_;
        float var  = l1[0] / (float)NEDGE_ - mean*mean;
        float sc = g[c] * rsqrtf(var + 1e-5f);
        scale[c] = sc;
        shift[c] = be[c] - mean*sc;
    }
}

// ---------------- fused global max-pool finalize ----------------
__global__ __launch_bounds__(1024) void gmax_finalize(
        const float* __restrict__ gp1, const float* __restrict__ gp2, const float* __restrict__ gp3,
        const float* __restrict__ sc1, const float* __restrict__ sh1,
        const float* __restrict__ sc2, const float* __restrict__ sh2,
        const float* __restrict__ sc3, const float* __restrict__ sh3,
        float* __restrict__ gfeat) {
    int b = blockIdx.x, grp = blockIdx.y;
    const float *gp, *sc, *sh; int C, c0, coff;
    if (grp == 0)      { gp = gp1; sc = sc1; sh = sh1; C = 64;  c0 = 0;            coff = 0;   }
    else if (grp <= 2) { gp = gp2; sc = sc2; sh = sh2; C = 128; c0 = (grp-1)*64;   coff = 64;  }
    else               { gp = gp3; sc = sc3; sh = sh3; C = 256; c0 = (grp-3)*64;   coff = 192; }
    int cl = threadIdx.x & 63;
    int stripe = threadIdx.x >> 6;   // 0..15
    int c = c0 + cl;
    float mx = -INFINITY;
    for (int ch = stripe; ch < CHUNKS_; ch += 16)
        mx = fmaxf(mx, gp[((size_t)b*CHUNKS_ + ch)*C + c]);
    __shared__ float red[16][64];
    red[stripe][cl] = mx;
    __syncthreads();
    for (int off = 8; off > 0; off >>= 1) {
        if (stripe < off) red[stripe][cl] = fmaxf(red[stripe][cl], red[stripe+off][cl]);
        __syncthreads();
    }
    if (stripe == 0)
        gfeat[b*448 + coff + c] = sc[c]*red[0][cl] + sh[c];
}

// ---------------- head part 1: H = BN(lrelu(gfeat@Wf1 + bf1)) ----------------
__global__ __launch_bounds__(256) void final1(const float* __restrict__ gfeat,
                                              const float* __restrict__ Wf1, const float* __restrict__ bf1,
                                              const float* __restrict__ gf, const float* __restrict__ bef,
                                              float* __restrict__ H) {
    __shared__ float gfs[B_][448];
    __shared__ float red[4][64][B_];
    int t = threadIdx.x;
    int cl = t & 63;
    int stripe = t >> 6;                 // 0..3
    int c = blockIdx.x * 64 + cl;
    for (int e = t; e < B_*448; e += 256) gfs[e/448][e%448] = gfeat[e];
    __syncthreads();
    float acc[B_] = {};
    for (int d = stripe*112; d < stripe*112 + 112; ++d) {
        float w = Wf1[(size_t)d*512 + c];
#pragma unroll
        for (int r = 0; r < B_; ++r) acc[r] += gfs[r][d] * w;
    }
#pragma unroll
    for (int r = 0; r < B_; ++r) red[stripe][cl][r] = acc[r];
    __syncthreads();
    if (stripe == 0) {
        float v[B_];
        float b1v = bf1[c];
#pragma unroll
        for (int r = 0; r < B_; ++r) {
            float a = red[0][cl][r] + red[1][cl][r] + red[2][cl][r] + red[3][cl][r] + b1v;
            v[r] = (a >= 0.f) ? a : 0.2f*a;
        }
        float mean = 0.f;
#pragma unroll
        for (int r = 0; r < B_; ++r) mean += v[r];
        mean *= (1.0f/B_);
        float var = 0.f;
#pragma unroll
        for (int r = 0; r < B_; ++r) { float dd = v[r] - mean; var += dd*dd; }
        var *= (1.0f/B_);
        float sc = gf[c] * rsqrtf(var + 1e-5f);
        float sh = bef[c] - mean*sc;
#pragma unroll
        for (int r = 0; r < B_; ++r) H[(size_t)r*512 + c] = v[r]*sc + sh;
    }
}

// ---------------- head part 2: out = H @ Wf2 + bf2 ----------------
__global__ __launch_bounds__(128) void final2(const float* __restrict__ H,
                                              const float* __restrict__ Wf2, const float* __restrict__ bf2,
                                              float* __restrict__ out) {
    int b = blockIdx.x, c = threadIdx.x;
    __shared__ float hs[512];
    for (int e = c; e < 512; e += 128) hs[e] = H[(size_t)b*512 + e];
    __syncthreads();
    float a = bf2[c];
    for (int d = 0; d < 512; ++d) a += hs[d] * Wf2[(size_t)d*128 + c];
    out[b*128 + c] = a;
}

// ---------------- host side ----------------
static void run_layer(int Kpad, int C,
                      const float* W, const float* g, const float* be, const float* b,
                      const float* scale_in, const float* shift_in,
                      float* PQ, const unsigned short* Xh_in, const unsigned short* Xl_in,
                      unsigned short* Xh_next, unsigned short* Xl_next,
                      unsigned short* WTh, unsigned short* WTl, float* cvec,
                      const int* src, float* partial, float* gpart,
                      float* scale_out, float* shift_out, hipStream_t stream) {
    int Cin = (scale_in == nullptr) ? IN_ : Kpad;   // layer1: Cin=5, else Cin==Kpad
    int nPrep = 2*C*Kpad + C;
    prep_layer<<<(nPrep + 255)/256, 256, 0, stream>>>(W, scale_in, shift_in, b, WTh, WTl, cvec, Cin, C, Kpad);
    mfma_dual<<<dim3(2*C/128, BN_/128), 256, 0, stream>>>(Xh_in, Xl_in, WTh, WTl, PQ, Kpad, 2*C);
    combine_kernel<<<BN_/GRP, C, 0, stream>>>(PQ, PQ + C, cvec, src, Xh_next, Xl_next, partial, gpart, C, 2*C);
    reduce_kernel<<<C, 256, 0, stream>>>(partial, BN_/GRP, C, g, be, scale_out, shift_out);
}

extern "C" void kernel_launch(void* const* d_in, const int* in_sizes, int n_in,
                              void* d_out, int out_size, void* d_ws, size_t ws_size,
                              hipStream_t stream) {
    (void)in_sizes; (void)n_in; (void)out_size; (void)ws_size;
    const float* points = (const float*)d_in[0];
    const float* W1 = (const float*)d_in[1];  const float* b1 = (const float*)d_in[2];
    const float* g1 = (const float*)d_in[3];  const float* be1 = (const float*)d_in[4];
    const float* W2 = (const float*)d_in[5];  const float* b2 = (const float*)d_in[6];
    const float* g2 = (const float*)d_in[7];  const float* be2 = (const float*)d_in[8];
    const float* W3 = (const float*)d_in[9];  const float* b3 = (const float*)d_in[10];
    const float* g3 = (const float*)d_in[11]; const float* be3 = (const float*)d_in[12];
    const float* Wf1 = (const float*)d_in[13]; const float* bf1 = (const float*)d_in[14];
    const float* gf = (const float*)d_in[15];  const float* bef = (const float*)d_in[16];
    const float* Wf2 = (const float*)d_in[17]; const float* bf2 = (const float*)d_in[18];
    float* out = (float*)d_out;

    size_t off = 0;
    char* base = (char*)d_ws;
    auto carve = [&](size_t bytes) -> void* {
        void* p = base + off;
        off += (bytes + 255) & ~(size_t)255;
        return p;
    };
    int*   src     = (int*)  carve((size_t)NEDGE_ * 4);
    float* PQ      = (float*)carve((size_t)BN_ * 512 * 4);   // 32MB; also kNN partial overlay
    float* gp1     = (float*)carve((size_t)(BN_/GRP) * 64 * 4);
    float* gp2     = (float*)carve((size_t)(BN_/GRP) * 128 * 4);
    float* gp3     = (float*)carve((size_t)(BN_/GRP) * 256 * 4);
    unsigned short* XhA = (unsigned short*)carve((size_t)BN_ * 128 * 2);
    unsigned short* XlA = (unsigned short*)carve((size_t)BN_ * 128 * 2);
    unsigned short* XhB = (unsigned short*)carve((size_t)BN_ * 128 * 2);
    unsigned short* XlB = (unsigned short*)carve((size_t)BN_ * 128 * 2);
    unsigned short* WTh = (unsigned short*)carve((size_t)512 * 128 * 2);
    unsigned short* WTl = (unsigned short*)carve((size_t)512 * 128 * 2);
    float4* P4     = (float4*)carve((size_t)BN_ * 16);
    float* cvec    = (float*)carve(256 * 4);
    float* sc1     = (float*)carve(64 * 4);
    float* sh1     = (float*)carve(64 * 4);
    float* sc2     = (float*)carve(128 * 4);
    float* sh2     = (float*)carve(128 * 4);
    float* sc3     = (float*)carve(256 * 4);
    float* sh3     = (float*)carve(256 * 4);
    float* partial = (float*)carve((size_t)(BN_/GRP) * 2 * 256 * 4);
    float* gfeat   = (float*)carve((size_t)B_ * 448 * 4);
    float* H       = (float*)carve((size_t)B_ * 512 * 4);

    // layer-1 cast + P4 pack first (knn reads P4)
    int total8 = BN_ * 32 / 8;
    cast_split<<<(total8 + 255)/256, 256, 0, stream>>>(points, XhA, XlA, P4, IN_, 32, total8);

    // kNN: phase-1 partials (SEG_*BN_*K_*8B = 32MB) overlay PQ (dead until first mfma_dual)
    unsigned long long* part = (unsigned long long*)PQ;
    knn_part<<<dim3(BN_/256, SEG_), 256, 0, stream>>>(P4, part);
    knn_merge<<<BN_/128, 128, 0, stream>>>(part, src);

    run_layer(32, 64,  W1, g1, be1, b1, nullptr, nullptr,
              PQ, XhA, XlA, XhB, XlB, WTh, WTl, cvec, src, partial, gp1, sc1, sh1, stream);
    run_layer(64, 128, W2, g2, be2, b2, sc1, sh1,
              PQ, XhB, XlB, XhA, XlA, WTh, WTl, cvec, src, partial, gp2, sc2, sh2, stream);
    run_layer(128, 256, W3, g3, be3, b3, sc2, sh2,
              PQ, XhA, XlA, nullptr, nullptr, WTh, WTl, cvec, src, partial, gp3, sc3, sh3, stream);

    gmax_finalize<<<dim3(B_, 7), 1024, 0, stream>>>(gp1, gp2, gp3,
                                                    sc1, sh1, sc2, sh2, sc3, sh3, gfeat);

    final1<<<8, 256, 0, stream>>>(gfeat, Wf1, bf1, gf, bef, H);
    final2<<<8, 128, 0, stream>>>(H, Wf2, bf2, out);
}

// Round 8
// 233.076 us; speedup vs baseline: 4.6808x; 1.0768x over previous
//
#include <hip/hip_runtime.h>
#include <math.h>

#define B_ 8
#define N_ 2048
#define K_ 8
#define IN_ 5
#define BN_ (B_*N_)
#define NEDGE_ (BN_*K_)
#define GRP 8
#define SEG_ 32
#define CSEG_ (N_/SEG_)   // 64 candidates per segment
#define CHUNKS_ (N_/GRP)  // 256 combine-blocks per batch

typedef unsigned short ushort8_ __attribute__((ext_vector_type(8)));
typedef short bf16x8_ __attribute__((ext_vector_type(8)));
typedef float f32x4_ __attribute__((ext_vector_type(4)));

// float -> bf16 (RNE), bf16 -> float
__device__ inline unsigned short f2bf(float f) {
    unsigned int u = __float_as_uint(f);
    u += 0x7fffu + ((u >> 16) & 1u);
    return (unsigned short)(u >> 16);
}
__device__ inline float bf2f(unsigned short h) {
    return __uint_as_float(((unsigned int)h) << 16);
}

// ordered-float: monotone map f32 -> u32
__device__ inline unsigned int ord_f32(float f) {
    unsigned int u = __float_as_uint(f);
    return (u & 0x80000000u) ? ~u : (u | 0x80000000u);
}

// ---------------- kNN phase 1: per-segment top-8; BRANCHLESS unconditional insert chain ----------------
__global__ __launch_bounds__(256) void knn_part(const float4* __restrict__ P4,
                                                unsigned long long* __restrict__ part) {
    int tid = threadIdx.x;
    int q = blockIdx.x * 256 + tid;     // block stays within one batch (2048 % 256 == 0)
    int b = q >> 11;                    // q / N_
    int nloc = q & (N_-1);              // local idx within batch
    int seg = blockIdx.y;

    float4 qp = P4[q];
    float qx2 = -2.0f*qp.x, qy2 = -2.0f*qp.y, qz2 = -2.0f*qp.z;
    float qsq = qp.w;

    unsigned long long best[K_];
#pragma unroll
    for (int k = 0; k < K_; ++k) best[k] = ~0ull;

    const float4* __restrict__ cb = P4 + (size_t)b*N_ + (size_t)seg*CSEG_;  // uniform base -> scalar loads
    int jbase = seg * CSEG_;

#pragma unroll 4
    for (int jj = 0; jj < CSEG_; ++jj) {
        float4 c = cb[jj];
        float d = qsq + c.w;
        d = fmaf(qx2, c.x, d);
        d = fmaf(qy2, c.y, d);
        d = fmaf(qz2, c.z, d);
        int jg = jbase + jj;
        d = (jg == nloc) ? INFINITY : d;   // self-exclusion; INF key always expelled (63 finite cands)
        unsigned long long cur = ((unsigned long long)ord_f32(d) << 32) | (unsigned int)jg;
        // unconditional 8-deep sorted insert: wave-wide the guard never skips, so
        // straight-line min/max cascade beats branching (no exec-mask churn)
#pragma unroll
        for (int p = 0; p < K_; ++p) {
            unsigned long long lo = best[p] < cur ? best[p] : cur;
            unsigned long long hi = best[p] < cur ? cur : best[p];
            best[p] = lo; cur = hi;
        }
    }
    unsigned long long* op = part + ((size_t)seg * BN_ + q) * K_;
#pragma unroll
    for (int k = 0; k < K_; ++k) op[k] = best[k];
}

// ---------------- kNN phase 2: merge SEG_ sorted 8-lists ----------------
__global__ __launch_bounds__(128) void knn_merge(const unsigned long long* __restrict__ part,
                                                 int* __restrict__ src) {
    int q = blockIdx.x * 128 + threadIdx.x;
    int b = q / N_;
    unsigned long long best[K_];
#pragma unroll
    for (int k = 0; k < K_; ++k) best[k] = ~0ull;
    for (int s = 0; s < SEG_; ++s) {
        const unsigned long long* lp = part + ((size_t)s * BN_ + q) * K_;
#pragma unroll
        for (int k = 0; k < K_; ++k) {
            unsigned long long key = lp[k];
            if (key >= best[K_-1]) break;   // lists sorted ascending -> rest are larger
            unsigned long long cur = key;
#pragma unroll
            for (int p = 0; p < K_; ++p) {
                unsigned long long lo = best[p] < cur ? best[p] : cur;
                unsigned long long hi = best[p] < cur ? cur : best[p];
                best[p] = lo; cur = hi;
            }
        }
    }
#pragma unroll
    for (int k = 0; k < K_; ++k)
        src[(size_t)q*K_ + k] = b*N_ + (int)(best[k] & 0xFFFFFFFFu);
}

// ---------------- layer-1 input cast + packed P4 build (runs FIRST) ----------------
__global__ __launch_bounds__(256) void cast_split(const float* __restrict__ X,
                                                  unsigned short* __restrict__ Xh,
                                                  unsigned short* __restrict__ Xl,
                                                  float4* __restrict__ P4,
                                                  int Kin, int Kpad, int total8) {
    int t = blockIdx.x * 256 + threadIdx.x;
    if (t < total8) {
        int vpr = Kpad >> 3;
        int m = t / vpr;
        int k0 = (t % vpr) * 8;
        ushort8_ vh, vl;
#pragma unroll
        for (int j = 0; j < 8; ++j) {
            int k = k0 + j;
            float v = (k < Kin) ? X[(size_t)m*Kin + k] : 0.0f;
            unsigned short h = f2bf(v);
            vh[j] = h;
            vl[j] = f2bf(v - bf2f(h));
        }
        *(ushort8_*)(Xh + (size_t)m*Kpad + k0) = vh;
        *(ushort8_*)(Xl + (size_t)m*Kpad + k0) = vl;
    }
    if (t < BN_) {
        const float* p = X + (size_t)t*Kin;
        float x = p[0], y = p[1], z = p[2];
        P4[t] = make_float4(x, y, z, x*x + y*y + z*z);
    }
}

// ---------------- fused weight prep: WT split-bf16 (BN fold) + c' vector ----------------
__global__ __launch_bounds__(256) void prep_layer(const float* __restrict__ W,
                                                  const float* __restrict__ scale,
                                                  const float* __restrict__ shift,
                                                  const float* __restrict__ bias,
                                                  unsigned short* __restrict__ WTh,
                                                  unsigned short* __restrict__ WTl,
                                                  float* __restrict__ cvec,
                                                  int Cin, int C, int Kpad) {
    int idx = blockIdx.x * 256 + threadIdx.x;
    int nWT = 2*C*Kpad;
    if (idx < nWT) {
        int n = idx / Kpad;
        int k = idx % Kpad;
        float val = 0.0f;
        if (k < Cin) {
            float s = scale ? scale[k] : 1.0f;
            if (n < C) val = s * (W[(size_t)k*C + n] - W[(size_t)(Cin+k)*C + n]);
            else       val = s * W[(size_t)(Cin+k)*C + (n - C)];
        }
        unsigned short h = f2bf(val);
        WTh[(size_t)n*Kpad + k] = h;
        WTl[(size_t)n*Kpad + k] = f2bf(val - bf2f(h));
    } else if (idx < nWT + C) {
        int c = idx - nWT;
        float acc = bias[c];
        if (shift)
            for (int d = 0; d < Cin; ++d) acc += shift[d] * W[(size_t)d*C + c];
        cvec[c] = acc;
    }
}

// ---------------- split-bf16 MFMA GEMM: PQ[M][Ntot] = X[M][K] @ WT^T, 128x128 tile, BK=32 ----------------
// 1-D grid, XCD-swizzled: all col-blocks of a row-panel land on XCD (y%8) for A-panel L2 reuse
__global__ __launch_bounds__(256) void mfma_dual(const unsigned short* __restrict__ Xh,
                                                 const unsigned short* __restrict__ Xl,
                                                 const unsigned short* __restrict__ WTh,
                                                 const unsigned short* __restrict__ WTl,
                                                 float* __restrict__ PQ, int K, int Ntot,
                                                 int gx) {
    __shared__ unsigned short sXh[128*32], sXl[128*32], sWh[128*32], sWl[128*32];
    int n = blockIdx.x;
    int by = (n & 7) + 8*(n/(8*gx));    // y%8 == n%8 == XCD
    int bx = (n >> 3) % gx;
    int tid = threadIdx.x, l = tid & 63, w = tid >> 6;
    int wr = w >> 1, wc = w & 1;                       // 2x2 waves -> 64x64 per wave
    int bm = by * 128, bn0 = bx * 128;

    f32x4_ acc[4][4];
#pragma unroll
    for (int i = 0; i < 4; ++i)
#pragma unroll
        for (int j = 0; j < 4; ++j) acc[i][j] = (f32x4_){0.f, 0.f, 0.f, 0.f};

    for (int k0 = 0; k0 < K; k0 += 32) {
#pragma unroll
        for (int i = 0; i < 2; ++i) {
            int idx = tid + i*256;                     // 0..511
            int row = idx >> 2;                        // 0..127
            int col0 = (idx & 3) * 8;                  // 0,8,16,24
            size_t gxo = (size_t)(bm  + row)*K + k0 + col0;
            size_t gwo = (size_t)(bn0 + row)*K + k0 + col0;
            int lo_ = ((row << 6) | (col0 << 1)) ^ ((row & 7) << 4);  // XOR swizzle
            *(ushort8_*)((char*)sXh + lo_) = *(const ushort8_*)(Xh + gxo);
            *(ushort8_*)((char*)sXl + lo_) = *(const ushort8_*)(Xl + gxo);
            *(ushort8_*)((char*)sWh + lo_) = *(const ushort8_*)(WTh + gwo);
            *(ushort8_*)((char*)sWl + lo_) = *(const ushort8_*)(WTl + gwo);
        }
        __syncthreads();

        int kb = (l >> 4) << 4;                        // byte offset of this lane's 8 k-elems
        bf16x8_ bh[4], bl4[4];
#pragma unroll
        for (int nf = 0; nf < 4; ++nf) {
            int rn = wc*64 + nf*16 + (l & 15);
            int o = ((rn << 6) | kb) ^ ((rn & 7) << 4);
            bh[nf]  = *(const bf16x8_*)((const char*)sWh + o);
            bl4[nf] = *(const bf16x8_*)((const char*)sWl + o);
        }
#pragma unroll
        for (int mf = 0; mf < 4; ++mf) {
            int rm = wr*64 + mf*16 + (l & 15);
            int o = ((rm << 6) | kb) ^ ((rm & 7) << 4);
            bf16x8_ ah = *(const bf16x8_*)((const char*)sXh + o);
            bf16x8_ al = *(const bf16x8_*)((const char*)sXl + o);
#pragma unroll
            for (int nf = 0; nf < 4; ++nf) {
                acc[mf][nf] = __builtin_amdgcn_mfma_f32_16x16x32_bf16(ah, bh[nf],  acc[mf][nf], 0, 0, 0);
                acc[mf][nf] = __builtin_amdgcn_mfma_f32_16x16x32_bf16(ah, bl4[nf], acc[mf][nf], 0, 0, 0);
                acc[mf][nf] = __builtin_amdgcn_mfma_f32_16x16x32_bf16(al, bh[nf],  acc[mf][nf], 0, 0, 0);
            }
        }
        __syncthreads();
    }

    int r0 = (l >> 4) << 2, cB = l & 15;
#pragma unroll
    for (int mf = 0; mf < 4; ++mf)
#pragma unroll
        for (int nf = 0; nf < 4; ++nf) {
            int col = bn0 + wc*64 + nf*16 + cB;
#pragma unroll
            for (int reg = 0; reg < 4; ++reg) {
                int row = bm + wr*64 + mf*16 + r0 + reg;
                PQ[(size_t)row*Ntot + col] = acc[mf][nf][reg];
            }
        }
}

// ---------------- edge combine: h = P[dst] + Q[src] + c ; lrelu; per-dst max -> split-bf16 X_next;
//                  BN partials; per-block partial max. XCD-swizzled: batch b -> XCD b ----------------
__global__ void combine_kernel(const float* __restrict__ P, const float* __restrict__ Q,
                               const float* __restrict__ cvec, const int* __restrict__ src,
                               unsigned short* __restrict__ Xh_out, unsigned short* __restrict__ Xl_out,
                               float* __restrict__ partial, float* __restrict__ gpart,
                               int C, int S) {
    int pb = blockIdx.x;
    int lb = (pb & 7) * CHUNKS_ + (pb >> 3);   // bijective: XCD (pb%8) gets all blocks of batch pb%8
    int c = threadIdx.x;                 // blockDim.x == C
    int i0 = lb * GRP;
    float cv = cvec[c];
    float sum = 0.f, ssq = 0.f;
    float bmx = -INFINITY;
    for (int g = 0; g < GRP; ++g) {
        int i = i0 + g;
        float p = P[(size_t)i*S + c] + cv;
        float mx = -INFINITY;
#pragma unroll
        for (int k = 0; k < K_; ++k) {
            int s = src[(size_t)i*K_ + k];
            float h = p + Q[(size_t)s*S + c];
            float l = (h >= 0.f) ? h : 0.2f*h;
            sum += l; ssq += l*l;
            mx = fmaxf(mx, l);
        }
        if (Xh_out) {                    // next layer's input, split-bf16 (Kpad_next == C)
            unsigned short hh = f2bf(mx);
            Xh_out[(size_t)i*C + c] = hh;
            Xl_out[(size_t)i*C + c] = f2bf(mx - bf2f(hh));
        }
        bmx = fmaxf(bmx, mx);
    }
    gpart[(size_t)lb*C + c] = bmx;
    partial[(size_t)lb*2*C + c]     = sum;
    partial[(size_t)lb*2*C + C + c] = ssq;
}

// ---------------- BN stats reduce -> scale/shift ----------------
__global__ __launch_bounds__(256) void reduce_kernel(const float* __restrict__ partial, int nblocks, int C,
                              const float* __restrict__ g, const float* __restrict__ be,
                              float* __restrict__ scale, float* __restrict__ shift) {
    int c = blockIdx.x;
    float s0 = 0.f, s1 = 0.f;
    for (int blk = threadIdx.x; blk < nblocks; blk += 256) {
        s0 += partial[(size_t)blk*2*C + c];
        s1 += partial[(size_t)blk*2*C + C + c];
    }
    __shared__ float l0[256], l1[256];
    l0[threadIdx.x] = s0; l1[threadIdx.x] = s1;
    __syncthreads();
    for (int off = 128; off > 0; off >>= 1) {
        if (threadIdx.x < off) {
            l0[threadIdx.x] += l0[threadIdx.x + off];
            l1[threadIdx.x] += l1[threadIdx.x + off];
        }
        __syncthreads();
    }
    if (threadIdx.x == 0) {
        float mean = l0[0] / (float)NEDGE_;
        float var  = l1[0] / (float)NEDGE_ - mean*mean;
        float sc = g[c] * rsqrtf(var + 1e-5f);
        scale[c] = sc;
        shift[c] = be[c] - mean*sc;
    }
}

// ---------------- fused global max-pool finalize ----------------
__global__ __launch_bounds__(1024) void gmax_finalize(
        const float* __restrict__ gp1, const float* __restrict__ gp2, const float* __restrict__ gp3,
        const float* __restrict__ sc1, const float* __restrict__ sh1,
        const float* __restrict__ sc2, const float* __restrict__ sh2,
        const float* __restrict__ sc3, const float* __restrict__ sh3,
        float* __restrict__ gfeat) {
    int b = blockIdx.x, grp = blockIdx.y;
    const float *gp, *sc, *sh; int C, c0, coff;
    if (grp == 0)      { gp = gp1; sc = sc1; sh = sh1; C = 64;  c0 = 0;            coff = 0;   }
    else if (grp <= 2) { gp = gp2; sc = sc2; sh = sh2; C = 128; c0 = (grp-1)*64;   coff = 64;  }
    else               { gp = gp3; sc = sc3; sh = sh3; C = 256; c0 = (grp-3)*64;   coff = 192; }
    int cl = threadIdx.x & 63;
    int stripe = threadIdx.x >> 6;   // 0..15
    int c = c0 + cl;
    float mx = -INFINITY;
    for (int ch = stripe; ch < CHUNKS_; ch += 16)
        mx = fmaxf(mx, gp[((size_t)b*CHUNKS_ + ch)*C + c]);
    __shared__ float red[16][64];
    red[stripe][cl] = mx;
    __syncthreads();
    for (int off = 8; off > 0; off >>= 1) {
        if (stripe < off) red[stripe][cl] = fmaxf(red[stripe][cl], red[stripe+off][cl]);
        __syncthreads();
    }
    if (stripe == 0)
        gfeat[b*448 + coff + c] = sc[c]*red[0][cl] + sh[c];
}

// ---------------- head part 1: H = BN(lrelu(gfeat@Wf1 + bf1)) ----------------
__global__ __launch_bounds__(256) void final1(const float* __restrict__ gfeat,
                                              const float* __restrict__ Wf1, const float* __restrict__ bf1,
                                              const float* __restrict__ gf, const float* __restrict__ bef,
                                              float* __restrict__ H) {
    __shared__ float gfs[B_][448];
    __shared__ float red[4][64][B_];
    int t = threadIdx.x;
    int cl = t & 63;
    int stripe = t >> 6;                 // 0..3
    int c = blockIdx.x * 64 + cl;
    for (int e = t; e < B_*448; e += 256) gfs[e/448][e%448] = gfeat[e];
    __syncthreads();
    float acc[B_] = {};
    for (int d = stripe*112; d < stripe*112 + 112; ++d) {
        float w = Wf1[(size_t)d*512 + c];
#pragma unroll
        for (int r = 0; r < B_; ++r) acc[r] += gfs[r][d] * w;
    }
#pragma unroll
    for (int r = 0; r < B_; ++r) red[stripe][cl][r] = acc[r];
    __syncthreads();
    if (stripe == 0) {
        float v[B_];
        float b1v = bf1[c];
#pragma unroll
        for (int r = 0; r < B_; ++r) {
            float a = red[0][cl][r] + red[1][cl][r] + red[2][cl][r] + red[3][cl][r] + b1v;
            v[r] = (a >= 0.f) ? a : 0.2f*a;
        }
        float mean = 0.f;
#pragma unroll
        for (int r = 0; r < B_; ++r) mean += v[r];
        mean *= (1.0f/B_);
        float var = 0.f;
#pragma unroll
        for (int r = 0; r < B_; ++r) { float dd = v[r] - mean; var += dd*dd; }
        var *= (1.0f/B_);
        float sc = gf[c] * rsqrtf(var + 1e-5f);
        float sh = bef[c] - mean*sc;
#pragma unroll
        for (int r = 0; r < B_; ++r) H[(size_t)r*512 + c] = v[r]*sc + sh;
    }
}

// ---------------- head part 2: out = H @ Wf2 + bf2 ----------------
__global__ __launch_bounds__(128) void final2(const float* __restrict__ H,
                                              const float* __restrict__ Wf2, const float* __restrict__ bf2,
                                              float* __restrict__ out) {
    int b = blockIdx.x, c = threadIdx.x;
    __shared__ float hs[512];
    for (int e = c; e < 512; e += 128) hs[e] = H[(size_t)b*512 + e];
    __syncthreads();
    float a = bf2[c];
    for (int d = 0; d < 512; ++d) a += hs[d] * Wf2[(size_t)d*128 + c];
    out[b*128 + c] = a;
}

// ---------------- host side ----------------
static void run_layer(int Kpad, int C,
                      const float* W, const float* g, const float* be, const float* b,
                      const float* scale_in, const float* shift_in,
                      float* PQ, const unsigned short* Xh_in, const unsigned short* Xl_in,
                      unsigned short* Xh_next, unsigned short* Xl_next,
                      unsigned short* WTh, unsigned short* WTl, float* cvec,
                      const int* src, float* partial, float* gpart,
                      float* scale_out, float* shift_out, hipStream_t stream) {
    int Cin = (scale_in == nullptr) ? IN_ : Kpad;   // layer1: Cin=5, else Cin==Kpad
    int nPrep = 2*C*Kpad + C;
    int gx = 2*C/128;
    prep_layer<<<(nPrep + 255)/256, 256, 0, stream>>>(W, scale_in, shift_in, b, WTh, WTl, cvec, Cin, C, Kpad);
    mfma_dual<<<gx*(BN_/128), 256, 0, stream>>>(Xh_in, Xl_in, WTh, WTl, PQ, Kpad, 2*C, gx);
    combine_kernel<<<BN_/GRP, C, 0, stream>>>(PQ, PQ + C, cvec, src, Xh_next, Xl_next, partial, gpart, C, 2*C);
    reduce_kernel<<<C, 256, 0, stream>>>(partial, BN_/GRP, C, g, be, scale_out, shift_out);
}

extern "C" void kernel_launch(void* const* d_in, const int* in_sizes, int n_in,
                              void* d_out, int out_size, void* d_ws, size_t ws_size,
                              hipStream_t stream) {
    (void)in_sizes; (void)n_in; (void)out_size; (void)ws_size;
    const float* points = (const float*)d_in[0];
    const float* W1 = (const float*)d_in[1];  const float* b1 = (const float*)d_in[2];
    const float* g1 = (const float*)d_in[3];  const float* be1 = (const float*)d_in[4];
    const float* W2 = (const float*)d_in[5];  const float* b2 = (const float*)d_in[6];
    const float* g2 = (const float*)d_in[7];  const float* be2 = (const float*)d_in[8];
    const float* W3 = (const float*)d_in[9];  const float* b3 = (const float*)d_in[10];
    const float* g3 = (const float*)d_in[11]; const float* be3 = (const float*)d_in[12];
    const float* Wf1 = (const float*)d_in[13]; const float* bf1 = (const float*)d_in[14];
    const float* gf = (const float*)d_in[15];  const float* bef = (const float*)d_in[16];
    const float* Wf2 = (const float*)d_in[17]; const float* bf2 = (const float*)d_in[18];
    float* out = (float*)d_out;

    size_t off = 0;
    char* base = (char*)d_ws;
    auto carve = [&](size_t bytes) -> void* {
        void* p = base + off;
        off += (bytes + 255) & ~(size_t)255;
        return p;
    };
    int*   src     = (int*)  carve((size_t)NEDGE_ * 4);
    float* PQ      = (float*)carve((size_t)BN_ * 512 * 4);   // 32MB; also kNN partial overlay
    float* gp1     = (float*)carve((size_t)(BN_/GRP) * 64 * 4);
    float* gp2     = (float*)carve((size_t)(BN_/GRP) * 128 * 4);
    float* gp3     = (float*)carve((size_t)(BN_/GRP) * 256 * 4);
    unsigned short* XhA = (unsigned short*)carve((size_t)BN_ * 128 * 2);
    unsigned short* XlA = (unsigned short*)carve((size_t)BN_ * 128 * 2);
    unsigned short* XhB = (unsigned short*)carve((size_t)BN_ * 128 * 2);
    unsigned short* XlB = (unsigned short*)carve((size_t)BN_ * 128 * 2);
    unsigned short* WTh = (unsigned short*)carve((size_t)512 * 128 * 2);
    unsigned short* WTl = (unsigned short*)carve((size_t)512 * 128 * 2);
    float4* P4     = (float4*)carve((size_t)BN_ * 16);
    float* cvec    = (float*)carve(256 * 4);
    float* sc1     = (float*)carve(64 * 4);
    float* sh1     = (float*)carve(64 * 4);
    float* sc2     = (float*)carve(128 * 4);
    float* sh2     = (float*)carve(128 * 4);
    float* sc3     = (float*)carve(256 * 4);
    float* sh3     = (float*)carve(256 * 4);
    float* partial = (float*)carve((size_t)(BN_/GRP) * 2 * 256 * 4);
    float* gfeat   = (float*)carve((size_t)B_ * 448 * 4);
    float* H       = (float*)carve((size_t)B_ * 512 * 4);

    // layer-1 cast + P4 pack first (knn reads P4)
    int total8 = BN_ * 32 / 8;
    cast_split<<<(total8 + 255)/256, 256, 0, stream>>>(points, XhA, XlA, P4, IN_, 32, total8);

    // kNN: phase-1 partials (SEG_*BN_*K_*8B = 32MB) overlay PQ (dead until first mfma_dual)
    unsigned long long* part = (unsigned long long*)PQ;
    knn_part<<<dim3(BN_/256, SEG_), 256, 0, stream>>>(P4, part);
    knn_merge<<<BN_/128, 128, 0, stream>>>(part, src);

    run_layer(32, 64,  W1, g1, be1, b1, nullptr, nullptr,
              PQ, XhA, XlA, XhB, XlB, WTh, WTl, cvec, src, partial, gp1, sc1, sh1, stream);
    run_layer(64, 128, W2, g2, be2, b2, sc1, sh1,
              PQ, XhB, XlB, XhA, XlA, WTh, WTl, cvec, src, partial, gp2, sc2, sh2, stream);
    run_layer(128, 256, W3, g3, be3, b3, sc2, sh2,
              PQ, XhA, XlA, nullptr, nullptr, WTh, WTl, cvec, src, partial, gp3, sc3, sh3, stream);

    gmax_finalize<<<dim3(B_, 7), 1024, 0, stream>>>(gp1, gp2, gp3,
                                                    sc1, sh1, sc2, sh2, sc3, sh3, gfeat);

    final1<<<8, 256, 0, stream>>>(gfeat, Wf1, bf1, gf, bef, H);
    final2<<<8, 128, 0, stream>>>(H, Wf2, bf2, out);
}